// Round 9
// baseline (310.094 us; speedup 1.0000x reference)
//
#include <hip/hip_runtime.h>
#include <hip/hip_bf16.h>
#include <hip/hip_cooperative_groups.h>

namespace cg = cooperative_groups;

// ---------------------------------------------------------------------------
// ResidualSAGEBlock: block-private bucket sort -> CSR(+offs) -> bf16 gather ->
// cooperative fused [MFMA dual GEMM -> BN stats -> BN -> +x -> ReLU].
// N=100000, D=128, E=1600000.
// R2: CSR gather replaced float-atomic scatter: 3095->812us.
// R3: gemm LDS 48->32KB, 5 blocks/CU: 812->761us.
// R4: multi-block scan (was 230us single-CU): 761->546us.
// R5: split gather from GEMM; MFMA bf16 GEMM; fused BN stats: 546->493us.
// R6 FAILED: global-atomic bucket append (cross-XCD line sharing): 493->757us.
// R7: 3-pass block-private counting sort: 757->409us.
// R8: bf16 gather source; offs folded into csrbuild; packed pairs: 409->306us.
// R9: cooperative fused tail (acc stays in registers across 2 grid syncs):
//     kills h write+read (102MB), x fp32 re-read, statreduce/bnparam/finalize
//     dispatches. b_l dropped (exactly cancelled by batch-stats BN).
// ---------------------------------------------------------------------------

#define D128 128
#define BSH2 8          // log2(nodes per bucket)
#define BSZ2 256        // nodes per bucket
#define MAXBUK 1024     // LDS bound for buckets (NBUK=391 actual)
#define SBLK 256        // sort blocks
#define CAP  5120       // csrbuild LDS capacity (mean 4096, +16 sigma)
#define RED  64         // reducer blocks in fused kernel

typedef short bf16x8 __attribute__((ext_vector_type(8)));
typedef float f32x4  __attribute__((ext_vector_type(4)));

static __device__ __forceinline__ unsigned short f2bf(float f) {
    unsigned u = __builtin_bit_cast(unsigned, f);
    unsigned r = u + 0x7fffu + ((u >> 16) & 1u);   // round-to-nearest-even
    return (unsigned short)(r >> 16);
}
static __device__ __forceinline__ float bflo(unsigned u) {   // low bf16 -> f32
    return __builtin_bit_cast(float, u << 16);
}
static __device__ __forceinline__ float bfhi(unsigned u) {   // high bf16 -> f32
    return __builtin_bit_cast(float, u & 0xffff0000u);
}
static __device__ __forceinline__ float bfs(unsigned short u) { // bf16 -> f32
    return __builtin_bit_cast(float, (unsigned)u << 16);
}

// --- build swizzled bf16 B for MFMA ----------------------------------------
// Bsw[t][c][lane][j] = Wcat[t*32 + (lane>>4)*8 + j][c*16 + (lane&15)]
// Wcat[k][d] = k<128 ? Wl[d][k] : Wr[d][k-128].
__global__ __launch_bounds__(256) void prep_kernel(
    const float* __restrict__ Wl, const float* __restrict__ Wr,
    unsigned short* __restrict__ Bsw) {
    int idx = blockIdx.x * 256 + threadIdx.x;   // 0..4095
    if (idx >= 4096) return;
    int l = idx & 63;
    int c = (idx >> 6) & 7;
    int t = idx >> 9;
    int d = c * 16 + (l & 15);
    int kbase = t * 32 + (l >> 4) * 8;
    unsigned short o[8];
#pragma unroll
    for (int j = 0; j < 8; ++j) {
        int k = kbase + j;
        float v = (k < 128) ? Wl[d * 128 + k] : Wr[d * 128 + (k - 128)];
        o[j] = f2bf(v);
    }
    *(uint4*)(Bsw + (size_t)idx * 8) = *(const uint4*)o;
}

// --- sort pass 1: per-block bucket histogram + fused x->bf16 conversion ----
__global__ __launch_bounds__(256) void bhist_kernel(
    const int* __restrict__ dst, int* __restrict__ ghist,
    const float* __restrict__ x, unsigned short* __restrict__ xb,
    int E, int chunk, int NBUK, int total4) {
    __shared__ int lh[MAXBUK];
    int tid = threadIdx.x;
    int b   = blockIdx.x;
    for (int i = tid; i < NBUK; i += 256) lh[i] = 0;
    __syncthreads();
    int beg = b * chunk;
    int end = min(beg + chunk, E);
    for (int i = beg + tid; i < end; i += 256)
        atomicAdd(&lh[dst[i] >> BSH2], 1);
    __syncthreads();
    for (int i = tid; i < NBUK; i += 256) ghist[i * SBLK + b] = lh[i];
    // fused streaming conversion x (fp32) -> xb (bf16)
    for (int i = b * 256 + tid; i < total4; i += 256 * SBLK) {
        float4 v = ((const float4*)x)[i];
        uint2 o;
        o.x = (unsigned)f2bf(v.x) | ((unsigned)f2bf(v.y) << 16);
        o.y = (unsigned)f2bf(v.z) | ((unsigned)f2bf(v.w) << 16);
        ((uint2*)xb)[i] = o;
    }
}

// --- scan stage 1: per-block (1024 elems) partial sums ---------------------
__global__ __launch_bounds__(256) void partial_kernel(const int* __restrict__ deg,
                                                      int* __restrict__ bsum, int N) {
    int tid  = threadIdx.x;
    int base = blockIdx.x * 1024 + tid * 4;
    int s = 0;
    if (base + 3 < N) {
        int4 v = *(const int4*)(deg + base);
        s = v.x + v.y + v.z + v.w;
    } else {
        for (int i = base; i < N; ++i) s += deg[i];
    }
    __shared__ int red[256];
    red[tid] = s;
    __syncthreads();
    for (int off = 128; off > 0; off >>= 1) {
        if (tid < off) red[tid] += red[tid + off];
        __syncthreads();
    }
    if (tid == 0) bsum[blockIdx.x] = red[0];
}

// --- scan stage 2: exclusive scan of block sums (NB <= 1024) ---------------
__global__ __launch_bounds__(1024) void scan_bsum_kernel(
    const int* __restrict__ bsum, int* __restrict__ ebsum,
    int NB, int* __restrict__ outN, int E) {
    __shared__ int buf[2][1024];
    int t = threadIdx.x;
    int v = (t < NB) ? bsum[t] : 0;
    buf[0][t] = v;
    __syncthreads();
    int pi = 0;
    for (int off = 1; off < 1024; off <<= 1) {
        int u = buf[pi][t];
        if (t >= off) u += buf[pi][t - off];
        buf[pi ^ 1][t] = u;
        __syncthreads();
        pi ^= 1;
    }
    if (t < NB) ebsum[t] = buf[pi][t] - v;   // exclusive prefix
    if (t == 0) *outN = E;
}

// --- scan stage 3: per-block exclusive scan + ebsum offset -----------------
__global__ __launch_bounds__(256) void scan_final_kernel(
    const int* __restrict__ deg, const int* __restrict__ ebsum,
    int* __restrict__ offs, int N) {
    int tid  = threadIdx.x;
    int base = blockIdx.x * 1024 + tid * 4;
    int d0 = 0, d1 = 0, d2 = 0, d3 = 0;
    if (base + 3 < N) {
        int4 v = *(const int4*)(deg + base);
        d0 = v.x; d1 = v.y; d2 = v.z; d3 = v.w;
    } else {
        if (base     < N) d0 = deg[base];
        if (base + 1 < N) d1 = deg[base + 1];
        if (base + 2 < N) d2 = deg[base + 2];
        if (base + 3 < N) d3 = deg[base + 3];
    }
    int s = d0 + d1 + d2 + d3;
    __shared__ int buf[2][256];
    buf[0][tid] = s;
    __syncthreads();
    int pi = 0;
    for (int off = 1; off < 256; off <<= 1) {
        int u = buf[pi][tid];
        if (tid >= off) u += buf[pi][tid - off];
        buf[pi ^ 1][tid] = u;
        __syncthreads();
        pi ^= 1;
    }
    int pre = buf[pi][tid] - s + ebsum[blockIdx.x];
    if (base + 3 < N) {
        int4 o = make_int4(pre, pre + d0, pre + d0 + d1, pre + d0 + d1 + d2);
        *(int4*)(offs + base) = o;
    } else {
        int p = pre;
        if (base     < N) { offs[base]     = p; p += d0; }
        if (base + 1 < N) { offs[base + 1] = p; p += d1; }
        if (base + 2 < N) { offs[base + 2] = p; p += d2; }
        if (base + 3 < N) { offs[base + 3] = p; }
    }
}

// --- sort pass 2: scatter packed (src<<8 | dst&255) into private ranges ----
__global__ __launch_bounds__(256) void bscatter_kernel(
    const int* __restrict__ src, const int* __restrict__ dst,
    const int* __restrict__ gsc, unsigned* __restrict__ pairs,
    int E, int chunk, int NBUK) {
    __shared__ int lcur[MAXBUK];
    int tid = threadIdx.x;
    int b   = blockIdx.x;
    for (int i = tid; i < NBUK; i += 256) lcur[i] = gsc[i * SBLK + b];
    __syncthreads();
    int beg = b * chunk;
    int end = min(beg + chunk, E);
    for (int i = beg + tid; i < end; i += 256) {
        int d = dst[i];
        int s = src[i];
        int pos = atomicAdd(&lcur[d >> BSH2], 1);
        pairs[pos] = ((unsigned)s << 8) | (unsigned)(d & 255);
    }
}

// --- per-bucket: local node histogram + scan -> offs; LDS sort -> csr ------
__global__ __launch_bounds__(256) void csrbuild_kernel(
    const unsigned* __restrict__ pairs, const int* __restrict__ gsc,
    int* __restrict__ csr, int* __restrict__ offs, int N, int NBUK, int E) {
    __shared__ int lcnt[BSZ2];
    __shared__ int sbuf[2][BSZ2];
    __shared__ int lcsr[CAP];
    int b   = blockIdx.x;
    int tid = threadIdx.x;
    int nlo = b << BSH2;
    int base = gsc[(size_t)b * SBLK];                       // bucket start
    int end  = (b + 1 < NBUK) ? gsc[(size_t)(b + 1) * SBLK] : E;
    int len  = end - base;
    lcnt[tid] = 0;
    __syncthreads();
    for (int i = tid; i < len; i += 256)
        atomicAdd(&lcnt[pairs[base + i] & 255u], 1);
    __syncthreads();
    int c = lcnt[tid];
    sbuf[0][tid] = c;
    __syncthreads();
    int pi = 0;
    for (int off = 1; off < 256; off <<= 1) {
        int u = sbuf[pi][tid];
        if (tid >= off) u += sbuf[pi][tid - off];
        sbuf[pi ^ 1][tid] = u;
        __syncthreads();
        pi ^= 1;
    }
    int pre = sbuf[pi][tid] - c;
    if (nlo + tid <= N) offs[nlo + tid] = base + pre;       // covers offs[N]=E
    lcnt[tid] = pre;                                        // reuse as cursor
    __syncthreads();
    if (len <= CAP) {
        for (int i = tid; i < len; i += 256) {
            unsigned p = pairs[base + i];
            int pos = atomicAdd(&lcnt[p & 255u], 1);
            lcsr[pos] = (int)(p >> 8);
        }
        __syncthreads();
        for (int i = tid; i < len; i += 256) csr[base + i] = lcsr[i];
    } else {
        for (int i = tid; i < len; i += 256) {
            unsigned p = pairs[base + i];
            int pos = atomicAdd(&lcnt[p & 255u], 1);
            csr[base + pos] = (int)(p >> 8);
        }
    }
}

// --- gather-mean from bf16 xb: aggb[n][:] = mean of xb[src] rows -----------
__global__ __launch_bounds__(256) void gather_kernel(
    const int* __restrict__ offs, const int* __restrict__ csr,
    const unsigned short* __restrict__ xb, unsigned short* __restrict__ aggb,
    int N, int Npad) {
    int tid  = threadIdx.x;
    int l    = tid & 31;
    int half = l >> 4;
    int fl   = l & 15;
    int n    = blockIdx.x * 8 + (tid >> 5);
    if (n >= Npad) return;
    float f[8] = {0.f, 0.f, 0.f, 0.f, 0.f, 0.f, 0.f, 0.f};
    float g[8] = {0.f, 0.f, 0.f, 0.f, 0.f, 0.f, 0.f, 0.f};
    float inv = 0.f;
    if (n < N) {
        int beg = offs[n], end = offs[n + 1];
        int deg = end - beg;
        int k = beg;
        for (; k + 4 <= end; k += 4) {
            int s0 = csr[k + half];
            int s1 = csr[k + 2 + half];
            uint4 v0 = *(const uint4*)(xb + (size_t)s0 * D128 + fl * 8);
            uint4 v1 = *(const uint4*)(xb + (size_t)s1 * D128 + fl * 8);
            f[0] += bflo(v0.x); f[1] += bfhi(v0.x);
            f[2] += bflo(v0.y); f[3] += bfhi(v0.y);
            f[4] += bflo(v0.z); f[5] += bfhi(v0.z);
            f[6] += bflo(v0.w); f[7] += bfhi(v0.w);
            g[0] += bflo(v1.x); g[1] += bfhi(v1.x);
            g[2] += bflo(v1.y); g[3] += bfhi(v1.y);
            g[4] += bflo(v1.z); g[5] += bfhi(v1.z);
            g[6] += bflo(v1.w); g[7] += bfhi(v1.w);
        }
        if (end - k >= 2) {
            int s0 = csr[k + half];
            uint4 v0 = *(const uint4*)(xb + (size_t)s0 * D128 + fl * 8);
            f[0] += bflo(v0.x); f[1] += bfhi(v0.x);
            f[2] += bflo(v0.y); f[3] += bfhi(v0.y);
            f[4] += bflo(v0.z); f[5] += bfhi(v0.z);
            f[6] += bflo(v0.w); f[7] += bfhi(v0.w);
            k += 2;
        }
        if (k < end && half == 0) {
            int s0 = csr[k];
            uint4 v0 = *(const uint4*)(xb + (size_t)s0 * D128 + fl * 8);
            f[0] += bflo(v0.x); f[1] += bfhi(v0.x);
            f[2] += bflo(v0.y); f[3] += bfhi(v0.y);
            f[4] += bflo(v0.z); f[5] += bfhi(v0.z);
            f[6] += bflo(v0.w); f[7] += bfhi(v0.w);
        }
        if (deg > 0) inv = 1.0f / (float)deg;
    }
#pragma unroll
    for (int j = 0; j < 8; ++j) {
        f[j] += g[j];
        f[j] += __shfl_xor(f[j], 16, 64);   // combine halves (stays in group)
    }
    if (half == 0) {
        uint4 o;
        o.x = (unsigned)f2bf(f[0] * inv) | ((unsigned)f2bf(f[1] * inv) << 16);
        o.y = (unsigned)f2bf(f[2] * inv) | ((unsigned)f2bf(f[3] * inv) << 16);
        o.z = (unsigned)f2bf(f[4] * inv) | ((unsigned)f2bf(f[5] * inv) << 16);
        o.w = (unsigned)f2bf(f[6] * inv) | ((unsigned)f2bf(f[7] * inv) << 16);
        *(uint4*)(aggb + (size_t)n * D128 + fl * 8) = o;
    }
}

// --- cooperative fused: MFMA GEMM -> pstat -> sync -> stats -> sync -> BN+out
// 128 thr = 2 waves; wave w owns 32 rows (2 x 16-row A-frags); 64 rows/block.
// K=256: ksteps 0-3 read aggb, 4-7 read xb. b_l omitted (cancelled by BN).
// acc registers survive the grid syncs; no h round-trip.
__global__ __launch_bounds__(128, 4) void fused_kernel(
    const unsigned short* __restrict__ aggb, const unsigned short* __restrict__ xb,
    const unsigned short* __restrict__ Bsw, const float* __restrict__ gamma,
    const float* __restrict__ beta, float* __restrict__ out,
    float* __restrict__ pstat, float* __restrict__ stats,
    int N, int NP, float invN) {
    int tid  = threadIdx.x;
    int w    = tid >> 6;
    int lane = tid & 63;
    int lc   = lane & 15;    // tile col
    int lq   = lane >> 4;    // quarter
    int rowBase = blockIdx.x * 64 + w * 32;

    f32x4 acc[2][8];
#pragma unroll
    for (int c = 0; c < 8; ++c) {
        f32x4 z = {0.f, 0.f, 0.f, 0.f};
        acc[0][c] = z;
        acc[1][c] = z;
    }

    int r0  = rowBase + lc;
    int r1  = rowBase + 16 + lc;
    int r0c = min(r0, N - 1);
    int r1c = min(r1, N - 1);

    for (int t = 0; t < 8; ++t) {
        const unsigned short* p0;
        const unsigned short* p1;
        if (t < 4) {
            int off = t * 32 + lq * 8;
            p0 = aggb + (size_t)r0 * D128 + off;
            p1 = aggb + (size_t)r1 * D128 + off;
        } else {
            int off = (t - 4) * 32 + lq * 8;
            p0 = xb + (size_t)r0c * D128 + off;
            p1 = xb + (size_t)r1c * D128 + off;
        }
        bf16x8 a0 = *(const bf16x8*)p0;
        bf16x8 a1 = *(const bf16x8*)p1;
#pragma unroll
        for (int c = 0; c < 8; ++c) {
            bf16x8 bf = *(const bf16x8*)(Bsw + ((size_t)((t * 8 + c) * 64 + lane)) * 8);
            acc[0][c] = __builtin_amdgcn_mfma_f32_16x16x32_bf16(a0, bf, acc[0][c], 0, 0, 0);
            acc[1][c] = __builtin_amdgcn_mfma_f32_16x16x32_bf16(a1, bf, acc[1][c], 0, 0, 0);
        }
    }

    // per-wave column partial sums -> pstat
    {
        float s[8], ss[8];
#pragma unroll
        for (int c = 0; c < 8; ++c) { s[c] = 0.f; ss[c] = 0.f; }
#pragma unroll
        for (int rh = 0; rh < 2; ++rh) {
#pragma unroll
            for (int reg = 0; reg < 4; ++reg) {
                int row = rowBase + rh * 16 + lq * 4 + reg;
                if (row < N) {
#pragma unroll
                    for (int c = 0; c < 8; ++c) {
                        float v = acc[rh][c][reg];
                        s[c]  += v;
                        ss[c] += v * v;
                    }
                }
            }
        }
#pragma unroll
        for (int c = 0; c < 8; ++c) {
            s[c]  += __shfl_xor(s[c], 16, 64);
            s[c]  += __shfl_xor(s[c], 32, 64);
            ss[c] += __shfl_xor(ss[c], 16, 64);
            ss[c] += __shfl_xor(ss[c], 32, 64);
        }
        if (lq == 0) {
            size_t prow = ((size_t)blockIdx.x * 2 + w) * 256;
#pragma unroll
            for (int c = 0; c < 8; ++c) {
                pstat[prow + c * 16 + lc]       = s[c];
                pstat[prow + 128 + c * 16 + lc] = ss[c];
            }
        }
    }

    __threadfence();                // flush dirty pstat lines out of local L2
    cg::this_grid().sync();

    // reduction by first RED blocks (agent-scope loads: pstat aliases csr,
    // whose lines may sit stale in this XCD's L2 from the gather kernel)
    if (blockIdx.x < RED) {
        float l0 = 0.f, l1 = 0.f;
        for (int r = blockIdx.x; r < NP; r += RED) {
            l0 += __hip_atomic_load(&pstat[(size_t)r * 256 + tid],
                                    __ATOMIC_RELAXED, __HIP_MEMORY_SCOPE_AGENT);
            l1 += __hip_atomic_load(&pstat[(size_t)r * 256 + 128 + tid],
                                    __ATOMIC_RELAXED, __HIP_MEMORY_SCOPE_AGENT);
        }
        atomicAdd(&stats[tid], l0);
        atomicAdd(&stats[128 + tid], l1);
    }

    __threadfence();
    cg::this_grid().sync();

    // per-block BN params from stats
    __shared__ float sscl[128];
    __shared__ float sshf[128];
    {
        int d = tid;   // 0..127
        float sum = __hip_atomic_load(&stats[d],
                                      __ATOMIC_RELAXED, __HIP_MEMORY_SCOPE_AGENT);
        float sq  = __hip_atomic_load(&stats[128 + d],
                                      __ATOMIC_RELAXED, __HIP_MEMORY_SCOPE_AGENT);
        float mean = sum * invN;
        float var  = sq * invN - mean * mean;
        float istd = rsqrtf(var + 1e-5f);
        float sc   = gamma[d] * istd;
        sscl[d] = sc;
        sshf[d] = beta[d] - mean * sc;
    }
    __syncthreads();

    // epilogue: BN + residual(bf16 x) + ReLU straight from registers
#pragma unroll
    for (int rh = 0; rh < 2; ++rh) {
#pragma unroll
        for (int reg = 0; reg < 4; ++reg) {
            int row = rowBase + rh * 16 + lq * 4 + reg;
            if (row < N) {
#pragma unroll
                for (int c = 0; c < 8; ++c) {
                    int col = c * 16 + lc;
                    float v  = acc[rh][c][reg];
                    float xv = bfs(xb[(size_t)row * D128 + col]);
                    float o  = fmaxf(fmaf(v, sscl[col], sshf[col]) + xv, 0.f);
                    out[(size_t)row * D128 + col] = o;
                }
            }
        }
    }
}

// ======================= fallback (R8) tail kernels ========================
__global__ __launch_bounds__(256) void mfma_kernel(
    const unsigned short* __restrict__ aggb, const unsigned short* __restrict__ xb,
    const unsigned short* __restrict__ Bsw, const float* __restrict__ bl,
    float* __restrict__ h, float* __restrict__ pstat, int N) {
    int tid  = threadIdx.x;
    int w    = tid >> 6;
    int lane = tid & 63;
    int lc   = lane & 15;
    int lq   = lane >> 4;
    int rowBase = blockIdx.x * 128 + w * 32;

    f32x4 acc[2][8];
#pragma unroll
    for (int c = 0; c < 8; ++c) {
        float b = bl[c * 16 + lc];
        f32x4 v = {b, b, b, b};
        acc[0][c] = v;
        acc[1][c] = v;
    }
    int r0  = rowBase + lc;
    int r1  = rowBase + 16 + lc;
    int r0c = min(r0, N - 1);
    int r1c = min(r1, N - 1);
    for (int t = 0; t < 8; ++t) {
        const unsigned short* p0;
        const unsigned short* p1;
        if (t < 4) {
            int off = t * 32 + lq * 8;
            p0 = aggb + (size_t)r0 * D128 + off;
            p1 = aggb + (size_t)r1 * D128 + off;
        } else {
            int off = (t - 4) * 32 + lq * 8;
            p0 = xb + (size_t)r0c * D128 + off;
            p1 = xb + (size_t)r1c * D128 + off;
        }
        bf16x8 a0 = *(const bf16x8*)p0;
        bf16x8 a1 = *(const bf16x8*)p1;
#pragma unroll
        for (int c = 0; c < 8; ++c) {
            bf16x8 bf = *(const bf16x8*)(Bsw + ((size_t)((t * 8 + c) * 64 + lane)) * 8);
            acc[0][c] = __builtin_amdgcn_mfma_f32_16x16x32_bf16(a0, bf, acc[0][c], 0, 0, 0);
            acc[1][c] = __builtin_amdgcn_mfma_f32_16x16x32_bf16(a1, bf, acc[1][c], 0, 0, 0);
        }
    }
    float s[8], ss[8];
#pragma unroll
    for (int c = 0; c < 8; ++c) { s[c] = 0.f; ss[c] = 0.f; }
#pragma unroll
    for (int rh = 0; rh < 2; ++rh) {
#pragma unroll
        for (int reg = 0; reg < 4; ++reg) {
            int row = rowBase + rh * 16 + lq * 4 + reg;
            if (row < N) {
#pragma unroll
                for (int c = 0; c < 8; ++c) {
                    float v = acc[rh][c][reg];
                    h[(size_t)row * D128 + c * 16 + lc] = v;
                    s[c]  += v;
                    ss[c] += v * v;
                }
            }
        }
    }
#pragma unroll
    for (int c = 0; c < 8; ++c) {
        s[c]  += __shfl_xor(s[c], 16, 64);
        s[c]  += __shfl_xor(s[c], 32, 64);
        ss[c] += __shfl_xor(ss[c], 16, 64);
        ss[c] += __shfl_xor(ss[c], 32, 64);
    }
    if (lq == 0) {
        size_t prow = ((size_t)blockIdx.x * 4 + w) * 256;
#pragma unroll
        for (int c = 0; c < 8; ++c) {
            pstat[prow + c * 16 + lc]       = s[c];
            pstat[prow + 128 + c * 16 + lc] = ss[c];
        }
    }
}

__global__ __launch_bounds__(256) void statreduce_kernel(
    const float* __restrict__ pstat, float* __restrict__ stats, int NP) {
    int tid = threadIdx.x;
    float loc = 0.f;
    for (int r = blockIdx.x; r < NP; r += gridDim.x)
        loc += pstat[(size_t)r * 256 + tid];
    atomicAdd(&stats[tid], loc);
}

__global__ void bnparam_kernel(const float* __restrict__ stats,
                               const float* __restrict__ gamma,
                               const float* __restrict__ beta,
                               float* __restrict__ scl, float* __restrict__ shf,
                               float invN) {
    int d = threadIdx.x;
    float mean = stats[d] * invN;
    float var  = stats[D128 + d] * invN - mean * mean;
    float istd = rsqrtf(var + 1e-5f);
    float sc   = gamma[d] * istd;
    scl[d] = sc;
    shf[d] = beta[d] - mean * sc;
}

__global__ __launch_bounds__(256) void finalize_kernel(
    const float* __restrict__ h, const float* __restrict__ x,
    const float* __restrict__ scl, const float* __restrict__ shf,
    float* __restrict__ out, long long total4) {
    long long i = (long long)blockIdx.x * 256 + threadIdx.x;
    if (i >= total4) return;
    int d = (int)((i * 4) & 127);
    float4 hv = ((const float4*)h)[i];
    float4 xv = ((const float4*)x)[i];
    float4 sc = *(const float4*)(scl + d);
    float4 sh = *(const float4*)(shf + d);
    float4 o;
    o.x = fmaxf(fmaf(hv.x, sc.x, sh.x) + xv.x, 0.f);
    o.y = fmaxf(fmaf(hv.y, sc.y, sh.y) + xv.y, 0.f);
    o.z = fmaxf(fmaf(hv.z, sc.z, sh.z) + xv.z, 0.f);
    o.w = fmaxf(fmaf(hv.w, sc.w, sh.w) + xv.w, 0.f);
    ((float4*)out)[i] = o;
}

extern "C" void kernel_launch(void* const* d_in, const int* in_sizes, int n_in,
                              void* d_out, int out_size, void* d_ws, size_t ws_size,
                              hipStream_t stream) {
    const float* x     = (const float*)d_in[0];
    const int*   eidx  = (const int*)d_in[1];
    const float* W_l   = (const float*)d_in[2];
    const float* b_l   = (const float*)d_in[3];
    const float* W_r   = (const float*)d_in[4];
    const float* gamma = (const float*)d_in[5];
    const float* beta  = (const float*)d_in[6];

    const int D = in_sizes[3];            // 128
    const int N = in_sizes[0] / D;        // 100000
    const int E = in_sizes[1] / 2;        // 1600000

    const int* src = eidx;
    const int* dst = eidx + E;

    const int NBLK  = (N + 127) / 128;        // fallback mfma blocks (782)
    const int Npad  = NBLK * 128;             // padded rows (100096)
    const int NBUK  = (N + BSZ2 - 1) / BSZ2;  // buckets (391)
    const int M     = NBUK * SBLK;            // ghist cells (100096)
    const int NB2   = (M + 1023) / 1024;      // ghist-scan blocks
    const int chunk = (E + SBLK - 1) / SBLK;  // edges per sort block (6250)
    const int total4 = N * D128 / 4;          // float4s in x
    const int GBLK  = (N + 63) / 64;          // fused blocks (1563)
    const int NPF   = GBLK * 2;               // fused pstat rows

    // workspace layout (byte cursor, 64B-aligned chunks)
    char* wp = (char*)d_ws;
    auto alloc = [&](size_t bytes) {
        char* p = wp;
        wp += (bytes + 63) & ~(size_t)63;
        return p;
    };
    float*    stats = (float*)   alloc(256 * 4);
    int*      offs  = (int*)     alloc((size_t)(N + 1) * 4);
    int*      csr   = (int*)     alloc((size_t)E * 4);        // reused as pstat
    unsigned* pairs = (unsigned*)alloc((size_t)E * 4);
    int*      ghist = (int*)     alloc((size_t)M * 4);
    int*      gsc   = (int*)     alloc((size_t)(M + 1) * 4);
    int*      bsum  = (int*)     alloc(1024 * 4);
    int*      ebsum = (int*)     alloc(1024 * 4);
    float*    scl   = (float*)   alloc(128 * 4);
    float*    shf   = (float*)   alloc(128 * 4);
    unsigned short* Bsw  = (unsigned short*)alloc(4096 * 16);
    unsigned short* xb   = (unsigned short*)alloc((size_t)N * D128 * 2);
    unsigned short* aggb = (unsigned short*)alloc((size_t)Npad * D128 * 2);
    float* pstat = (float*)csr;                               // after gather

    float* outp = (float*)d_out;
    float invN = 1.0f / (float)N;

    hipMemsetAsync(stats, 0, 256 * sizeof(float), stream);

    prep_kernel<<<16, 256, 0, stream>>>(W_l, W_r, Bsw);

    // bucket hist (+ fused x->bf16) -> scan -> block-private scatter
    bhist_kernel<<<SBLK, 256, 0, stream>>>(dst, ghist, x, xb, E, chunk, NBUK, total4);
    partial_kernel<<<NB2, 256, 0, stream>>>(ghist, bsum, M);
    scan_bsum_kernel<<<1, 1024, 0, stream>>>(bsum, ebsum, NB2, gsc + M, E);
    scan_final_kernel<<<NB2, 256, 0, stream>>>(ghist, ebsum, gsc, M);
    bscatter_kernel<<<SBLK, 256, 0, stream>>>(src, dst, gsc, pairs, E, chunk, NBUK);

    // per-bucket CSR build (also writes offs)
    csrbuild_kernel<<<NBUK, 256, 0, stream>>>(pairs, gsc, csr, offs, N, NBUK, E);

    gather_kernel<<<Npad / 8, 256, 0, stream>>>(offs, csr, xb, aggb, N, Npad);

    // cooperative fused tail if the grid is co-resident; else R8 fallback
    int blocksPerCU = 0;
    hipOccupancyMaxActiveBlocksPerMultiprocessor(&blocksPerCU,
        reinterpret_cast<const void*>(fused_kernel), 128, 0);
    bool coop = (blocksPerCU * 256 >= GBLK);   // 256 CUs on MI355X

    if (coop) {
        int np = NPF;
        void* args[] = {(void*)&aggb, (void*)&xb, (void*)&Bsw, (void*)&gamma,
                        (void*)&beta, (void*)&outp, (void*)&pstat, (void*)&stats,
                        (void*)&N, (void*)&np, (void*)&invN};
        hipLaunchCooperativeKernel(reinterpret_cast<const void*>(fused_kernel),
                                   dim3(GBLK), dim3(128), args, 0, stream);
    } else {
        float* h = outp;   // stage h in d_out, finalize in place
        mfma_kernel<<<NBLK, 256, 0, stream>>>(aggb, xb, Bsw, b_l, h, pstat, N);
        statreduce_kernel<<<64, 256, 0, stream>>>(pstat, stats, NBLK * 4);
        bnparam_kernel<<<1, 128, 0, stream>>>(stats, gamma, beta, scl, shf, invN);
        long long t4 = (long long)N * D128 / 4;
        finalize_kernel<<<(int)((t4 + 255) / 256), 256, 0, stream>>>(
            h, x, scl, shf, outp, t4);
    }
}

// Round 10
// 303.123 us; speedup vs baseline: 1.0230x; 1.0230x over previous
//
#include <hip/hip_runtime.h>
#include <hip/hip_bf16.h>

// ---------------------------------------------------------------------------
// ResidualSAGEBlock: block-private bucket sort -> CSR(+offs) -> bf16 gather ->
// MFMA bf16 dual GEMM (+fused BN stats) -> statreduce -> finalize(BN+res+ReLU).
// N=100000, D=128, E=1600000.
// R2: CSR gather replaced float-atomic scatter: 3095->812us.
// R3: gemm LDS 48->32KB, 5 blocks/CU: 812->761us.
// R4: multi-block scan (was 230us single-CU): 761->546us.
// R5: split gather from GEMM; MFMA bf16 GEMM; fused BN stats: 546->493us.
// R6 FAILED: global-atomic bucket append (cross-XCD line sharing): 493->757us.
// R7: 3-pass block-private counting sort: 757->409us.
// R8: bf16 gather source; offs folded into csrbuild; packed pairs: 409->306us.
// R9 FAILED: cooperative fused tail -- cg grid.sync costs ~370us at 1563
//     blocks on MI355X (fused dispatch alone 400us): 306->310us. NEVER
//     replace a ~45us 3-dispatch tail with grid-wide sync at this scale.
// R10: revert to R8 tail; h stored bf16 (halves h traffic); finalize reads
//      bf16 xb for residual; bnparam folded into finalize; b_l dropped
//      (exactly cancelled by training-mode BN).
// ---------------------------------------------------------------------------

#define D128 128
#define BSH2 8          // log2(nodes per bucket)
#define BSZ2 256        // nodes per bucket
#define MAXBUK 1024     // LDS bound for buckets (NBUK=391 actual)
#define SBLK 256        // sort blocks
#define CAP  5120       // csrbuild LDS capacity (mean 4096, +16 sigma)

typedef short bf16x8 __attribute__((ext_vector_type(8)));
typedef float f32x4  __attribute__((ext_vector_type(4)));

static __device__ __forceinline__ unsigned short f2bf(float f) {
    unsigned u = __builtin_bit_cast(unsigned, f);
    unsigned r = u + 0x7fffu + ((u >> 16) & 1u);   // round-to-nearest-even
    return (unsigned short)(r >> 16);
}
static __device__ __forceinline__ float bflo(unsigned u) {   // low bf16 -> f32
    return __builtin_bit_cast(float, u << 16);
}
static __device__ __forceinline__ float bfhi(unsigned u) {   // high bf16 -> f32
    return __builtin_bit_cast(float, u & 0xffff0000u);
}

// --- build swizzled bf16 B for MFMA ----------------------------------------
// Bsw[t][c][lane][j] = Wcat[t*32 + (lane>>4)*8 + j][c*16 + (lane&15)]
// Wcat[k][d] = k<128 ? Wl[d][k] : Wr[d][k-128].
__global__ __launch_bounds__(256) void prep_kernel(
    const float* __restrict__ Wl, const float* __restrict__ Wr,
    unsigned short* __restrict__ Bsw) {
    int idx = blockIdx.x * 256 + threadIdx.x;   // 0..4095
    if (idx >= 4096) return;
    int l = idx & 63;
    int c = (idx >> 6) & 7;
    int t = idx >> 9;
    int d = c * 16 + (l & 15);
    int kbase = t * 32 + (l >> 4) * 8;
    unsigned short o[8];
#pragma unroll
    for (int j = 0; j < 8; ++j) {
        int k = kbase + j;
        float v = (k < 128) ? Wl[d * 128 + k] : Wr[d * 128 + (k - 128)];
        o[j] = f2bf(v);
    }
    *(uint4*)(Bsw + (size_t)idx * 8) = *(const uint4*)o;
}

// --- sort pass 1: per-block bucket histogram + fused x->bf16 conversion ----
__global__ __launch_bounds__(256) void bhist_kernel(
    const int* __restrict__ dst, int* __restrict__ ghist,
    const float* __restrict__ x, unsigned short* __restrict__ xb,
    int E, int chunk, int NBUK, int total4) {
    __shared__ int lh[MAXBUK];
    int tid = threadIdx.x;
    int b   = blockIdx.x;
    for (int i = tid; i < NBUK; i += 256) lh[i] = 0;
    __syncthreads();
    int beg = b * chunk;
    int end = min(beg + chunk, E);
    for (int i = beg + tid; i < end; i += 256)
        atomicAdd(&lh[dst[i] >> BSH2], 1);
    __syncthreads();
    for (int i = tid; i < NBUK; i += 256) ghist[i * SBLK + b] = lh[i];
    // fused streaming conversion x (fp32) -> xb (bf16)
    for (int i = b * 256 + tid; i < total4; i += 256 * SBLK) {
        float4 v = ((const float4*)x)[i];
        uint2 o;
        o.x = (unsigned)f2bf(v.x) | ((unsigned)f2bf(v.y) << 16);
        o.y = (unsigned)f2bf(v.z) | ((unsigned)f2bf(v.w) << 16);
        ((uint2*)xb)[i] = o;
    }
}

// --- scan stage 1: per-block (1024 elems) partial sums ---------------------
__global__ __launch_bounds__(256) void partial_kernel(const int* __restrict__ deg,
                                                      int* __restrict__ bsum, int N) {
    int tid  = threadIdx.x;
    int base = blockIdx.x * 1024 + tid * 4;
    int s = 0;
    if (base + 3 < N) {
        int4 v = *(const int4*)(deg + base);
        s = v.x + v.y + v.z + v.w;
    } else {
        for (int i = base; i < N; ++i) s += deg[i];
    }
    __shared__ int red[256];
    red[tid] = s;
    __syncthreads();
    for (int off = 128; off > 0; off >>= 1) {
        if (tid < off) red[tid] += red[tid + off];
        __syncthreads();
    }
    if (tid == 0) bsum[blockIdx.x] = red[0];
}

// --- scan stage 2: exclusive scan of block sums (NB <= 1024) ---------------
__global__ __launch_bounds__(1024) void scan_bsum_kernel(
    const int* __restrict__ bsum, int* __restrict__ ebsum,
    int NB, int* __restrict__ outN, int E) {
    __shared__ int buf[2][1024];
    int t = threadIdx.x;
    int v = (t < NB) ? bsum[t] : 0;
    buf[0][t] = v;
    __syncthreads();
    int pi = 0;
    for (int off = 1; off < 1024; off <<= 1) {
        int u = buf[pi][t];
        if (t >= off) u += buf[pi][t - off];
        buf[pi ^ 1][t] = u;
        __syncthreads();
        pi ^= 1;
    }
    if (t < NB) ebsum[t] = buf[pi][t] - v;   // exclusive prefix
    if (t == 0) *outN = E;
}

// --- scan stage 3: per-block exclusive scan + ebsum offset -----------------
__global__ __launch_bounds__(256) void scan_final_kernel(
    const int* __restrict__ deg, const int* __restrict__ ebsum,
    int* __restrict__ offs, int N) {
    int tid  = threadIdx.x;
    int base = blockIdx.x * 1024 + tid * 4;
    int d0 = 0, d1 = 0, d2 = 0, d3 = 0;
    if (base + 3 < N) {
        int4 v = *(const int4*)(deg + base);
        d0 = v.x; d1 = v.y; d2 = v.z; d3 = v.w;
    } else {
        if (base     < N) d0 = deg[base];
        if (base + 1 < N) d1 = deg[base + 1];
        if (base + 2 < N) d2 = deg[base + 2];
        if (base + 3 < N) d3 = deg[base + 3];
    }
    int s = d0 + d1 + d2 + d3;
    __shared__ int buf[2][256];
    buf[0][tid] = s;
    __syncthreads();
    int pi = 0;
    for (int off = 1; off < 256; off <<= 1) {
        int u = buf[pi][tid];
        if (tid >= off) u += buf[pi][tid - off];
        buf[pi ^ 1][tid] = u;
        __syncthreads();
        pi ^= 1;
    }
    int pre = buf[pi][tid] - s + ebsum[blockIdx.x];
    if (base + 3 < N) {
        int4 o = make_int4(pre, pre + d0, pre + d0 + d1, pre + d0 + d1 + d2);
        *(int4*)(offs + base) = o;
    } else {
        int p = pre;
        if (base     < N) { offs[base]     = p; p += d0; }
        if (base + 1 < N) { offs[base + 1] = p; p += d1; }
        if (base + 2 < N) { offs[base + 2] = p; p += d2; }
        if (base + 3 < N) { offs[base + 3] = p; }
    }
}

// --- sort pass 2: scatter packed (src<<8 | dst&255) into private ranges ----
__global__ __launch_bounds__(256) void bscatter_kernel(
    const int* __restrict__ src, const int* __restrict__ dst,
    const int* __restrict__ gsc, unsigned* __restrict__ pairs,
    int E, int chunk, int NBUK) {
    __shared__ int lcur[MAXBUK];
    int tid = threadIdx.x;
    int b   = blockIdx.x;
    for (int i = tid; i < NBUK; i += 256) lcur[i] = gsc[i * SBLK + b];
    __syncthreads();
    int beg = b * chunk;
    int end = min(beg + chunk, E);
    for (int i = beg + tid; i < end; i += 256) {
        int d = dst[i];
        int s = src[i];
        int pos = atomicAdd(&lcur[d >> BSH2], 1);
        pairs[pos] = ((unsigned)s << 8) | (unsigned)(d & 255);
    }
}

// --- per-bucket: local node histogram + scan -> offs; LDS sort -> csr ------
__global__ __launch_bounds__(256) void csrbuild_kernel(
    const unsigned* __restrict__ pairs, const int* __restrict__ gsc,
    int* __restrict__ csr, int* __restrict__ offs, int N, int NBUK, int E) {
    __shared__ int lcnt[BSZ2];
    __shared__ int sbuf[2][BSZ2];
    __shared__ int lcsr[CAP];
    int b   = blockIdx.x;
    int tid = threadIdx.x;
    int nlo = b << BSH2;
    int base = gsc[(size_t)b * SBLK];                       // bucket start
    int end  = (b + 1 < NBUK) ? gsc[(size_t)(b + 1) * SBLK] : E;
    int len  = end - base;
    lcnt[tid] = 0;
    __syncthreads();
    for (int i = tid; i < len; i += 256)
        atomicAdd(&lcnt[pairs[base + i] & 255u], 1);
    __syncthreads();
    int c = lcnt[tid];
    sbuf[0][tid] = c;
    __syncthreads();
    int pi = 0;
    for (int off = 1; off < 256; off <<= 1) {
        int u = sbuf[pi][tid];
        if (tid >= off) u += sbuf[pi][tid - off];
        sbuf[pi ^ 1][tid] = u;
        __syncthreads();
        pi ^= 1;
    }
    int pre = sbuf[pi][tid] - c;
    if (nlo + tid <= N) offs[nlo + tid] = base + pre;       // covers offs[N]=E
    lcnt[tid] = pre;                                        // reuse as cursor
    __syncthreads();
    if (len <= CAP) {
        for (int i = tid; i < len; i += 256) {
            unsigned p = pairs[base + i];
            int pos = atomicAdd(&lcnt[p & 255u], 1);
            lcsr[pos] = (int)(p >> 8);
        }
        __syncthreads();
        for (int i = tid; i < len; i += 256) csr[base + i] = lcsr[i];
    } else {
        for (int i = tid; i < len; i += 256) {
            unsigned p = pairs[base + i];
            int pos = atomicAdd(&lcnt[p & 255u], 1);
            csr[base + pos] = (int)(p >> 8);
        }
    }
}

// --- gather-mean from bf16 xb: aggb[n][:] = mean of xb[src] rows -----------
__global__ __launch_bounds__(256) void gather_kernel(
    const int* __restrict__ offs, const int* __restrict__ csr,
    const unsigned short* __restrict__ xb, unsigned short* __restrict__ aggb,
    int N, int Npad) {
    int tid  = threadIdx.x;
    int l    = tid & 31;
    int half = l >> 4;
    int fl   = l & 15;
    int n    = blockIdx.x * 8 + (tid >> 5);
    if (n >= Npad) return;
    float f[8] = {0.f, 0.f, 0.f, 0.f, 0.f, 0.f, 0.f, 0.f};
    float g[8] = {0.f, 0.f, 0.f, 0.f, 0.f, 0.f, 0.f, 0.f};
    float inv = 0.f;
    if (n < N) {
        int beg = offs[n], end = offs[n + 1];
        int deg = end - beg;
        int k = beg;
        for (; k + 4 <= end; k += 4) {
            int s0 = csr[k + half];
            int s1 = csr[k + 2 + half];
            uint4 v0 = *(const uint4*)(xb + (size_t)s0 * D128 + fl * 8);
            uint4 v1 = *(const uint4*)(xb + (size_t)s1 * D128 + fl * 8);
            f[0] += bflo(v0.x); f[1] += bfhi(v0.x);
            f[2] += bflo(v0.y); f[3] += bfhi(v0.y);
            f[4] += bflo(v0.z); f[5] += bfhi(v0.z);
            f[6] += bflo(v0.w); f[7] += bfhi(v0.w);
            g[0] += bflo(v1.x); g[1] += bfhi(v1.x);
            g[2] += bflo(v1.y); g[3] += bfhi(v1.y);
            g[4] += bflo(v1.z); g[5] += bfhi(v1.z);
            g[6] += bflo(v1.w); g[7] += bfhi(v1.w);
        }
        if (end - k >= 2) {
            int s0 = csr[k + half];
            uint4 v0 = *(const uint4*)(xb + (size_t)s0 * D128 + fl * 8);
            f[0] += bflo(v0.x); f[1] += bfhi(v0.x);
            f[2] += bflo(v0.y); f[3] += bfhi(v0.y);
            f[4] += bflo(v0.z); f[5] += bfhi(v0.z);
            f[6] += bflo(v0.w); f[7] += bfhi(v0.w);
            k += 2;
        }
        if (k < end && half == 0) {
            int s0 = csr[k];
            uint4 v0 = *(const uint4*)(xb + (size_t)s0 * D128 + fl * 8);
            f[0] += bflo(v0.x); f[1] += bfhi(v0.x);
            f[2] += bflo(v0.y); f[3] += bfhi(v0.y);
            f[4] += bflo(v0.z); f[5] += bfhi(v0.z);
            f[6] += bflo(v0.w); f[7] += bfhi(v0.w);
        }
        if (deg > 0) inv = 1.0f / (float)deg;
    }
#pragma unroll
    for (int j = 0; j < 8; ++j) {
        f[j] += g[j];
        f[j] += __shfl_xor(f[j], 16, 64);   // combine halves (stays in group)
    }
    if (half == 0) {
        uint4 o;
        o.x = (unsigned)f2bf(f[0] * inv) | ((unsigned)f2bf(f[1] * inv) << 16);
        o.y = (unsigned)f2bf(f[2] * inv) | ((unsigned)f2bf(f[3] * inv) << 16);
        o.z = (unsigned)f2bf(f[4] * inv) | ((unsigned)f2bf(f[5] * inv) << 16);
        o.w = (unsigned)f2bf(f[6] * inv) | ((unsigned)f2bf(f[7] * inv) << 16);
        *(uint4*)(aggb + (size_t)n * D128 + fl * 8) = o;
    }
}

// --- MFMA dual GEMM -> bf16 h + fused BN partial stats ---------------------
// K=256: ksteps 0-3 read aggb, 4-7 read xb. No b_l (cancelled by BN).
__global__ __launch_bounds__(256) void mfma_kernel(
    const unsigned short* __restrict__ aggb, const unsigned short* __restrict__ xb,
    const unsigned short* __restrict__ Bsw,
    unsigned short* __restrict__ h16, float* __restrict__ pstat, int N) {
    int tid  = threadIdx.x;
    int w    = tid >> 6;
    int lane = tid & 63;
    int lc   = lane & 15;    // tile col
    int lq   = lane >> 4;    // quarter
    int rowBase = blockIdx.x * 128 + w * 32;

    f32x4 acc[2][8];
#pragma unroll
    for (int c = 0; c < 8; ++c) {
        f32x4 z = {0.f, 0.f, 0.f, 0.f};
        acc[0][c] = z;
        acc[1][c] = z;
    }
    int r0  = rowBase + lc;
    int r1  = rowBase + 16 + lc;
    int r0c = min(r0, N - 1);
    int r1c = min(r1, N - 1);
    for (int t = 0; t < 8; ++t) {
        const unsigned short* p0;
        const unsigned short* p1;
        if (t < 4) {
            int off = t * 32 + lq * 8;
            p0 = aggb + (size_t)r0 * D128 + off;
            p1 = aggb + (size_t)r1 * D128 + off;
        } else {
            int off = (t - 4) * 32 + lq * 8;
            p0 = xb + (size_t)r0c * D128 + off;
            p1 = xb + (size_t)r1c * D128 + off;
        }
        bf16x8 a0 = *(const bf16x8*)p0;
        bf16x8 a1 = *(const bf16x8*)p1;
#pragma unroll
        for (int c = 0; c < 8; ++c) {
            bf16x8 bf = *(const bf16x8*)(Bsw + ((size_t)((t * 8 + c) * 64 + lane)) * 8);
            acc[0][c] = __builtin_amdgcn_mfma_f32_16x16x32_bf16(a0, bf, acc[0][c], 0, 0, 0);
            acc[1][c] = __builtin_amdgcn_mfma_f32_16x16x32_bf16(a1, bf, acc[1][c], 0, 0, 0);
        }
    }
    float s[8], ss[8];
#pragma unroll
    for (int c = 0; c < 8; ++c) { s[c] = 0.f; ss[c] = 0.f; }
#pragma unroll
    for (int rh = 0; rh < 2; ++rh) {
#pragma unroll
        for (int reg = 0; reg < 4; ++reg) {
            int row = rowBase + rh * 16 + lq * 4 + reg;   // C-layout row
            if (row < N) {
#pragma unroll
                for (int c = 0; c < 8; ++c) {
                    float v = acc[rh][c][reg];
                    h16[(size_t)row * D128 + c * 16 + lc] = f2bf(v);
                    s[c]  += v;
                    ss[c] += v * v;
                }
            }
        }
    }
#pragma unroll
    for (int c = 0; c < 8; ++c) {
        s[c]  += __shfl_xor(s[c], 16, 64);
        s[c]  += __shfl_xor(s[c], 32, 64);
        ss[c] += __shfl_xor(ss[c], 16, 64);
        ss[c] += __shfl_xor(ss[c], 32, 64);
    }
    if (lq == 0) {
        size_t prow = ((size_t)blockIdx.x * 4 + w) * 256;
#pragma unroll
        for (int c = 0; c < 8; ++c) {
            pstat[prow + c * 16 + lc]       = s[c];
            pstat[prow + 128 + c * 16 + lc] = ss[c];
        }
    }
}

// --- reduce per-wave partial stats -> stats[256] ---------------------------
__global__ __launch_bounds__(256) void statreduce_kernel(
    const float* __restrict__ pstat, float* __restrict__ stats, int NP) {
    int tid = threadIdx.x;
    float loc = 0.f;
    for (int r = blockIdx.x; r < NP; r += gridDim.x)
        loc += pstat[(size_t)r * 256 + tid];
    atomicAdd(&stats[tid], loc);
}

// --- finalize: BN params in LDS, out = relu(h16*scl + shf + xb) ------------
// thread i handles 4 consecutive cols: uint2 h16 + uint2 xb -> float4 out.
__global__ __launch_bounds__(256) void finalize_kernel(
    const unsigned short* __restrict__ h16, const unsigned short* __restrict__ xb,
    const float* __restrict__ stats, const float* __restrict__ gamma,
    const float* __restrict__ beta, float* __restrict__ out,
    long long total4, float invN) {
    __shared__ float sscl[D128];
    __shared__ float sshf[D128];
    int tid = threadIdx.x;
    if (tid < D128) {
        float mean = stats[tid] * invN;
        float var  = stats[D128 + tid] * invN - mean * mean;
        float istd = rsqrtf(var + 1e-5f);
        float sc   = gamma[tid] * istd;
        sscl[tid] = sc;
        sshf[tid] = beta[tid] - mean * sc;
    }
    __syncthreads();
    long long i = (long long)blockIdx.x * 256 + tid;
    if (i >= total4) return;
    int d = (int)((i * 4) & 127);
    uint2 hv = ((const uint2*)h16)[i];
    uint2 xv = ((const uint2*)xb)[i];
    float4 o;
    o.x = fmaxf(fmaf(bflo(hv.x), sscl[d],     sshf[d])     + bflo(xv.x), 0.f);
    o.y = fmaxf(fmaf(bfhi(hv.x), sscl[d + 1], sshf[d + 1]) + bfhi(xv.x), 0.f);
    o.z = fmaxf(fmaf(bflo(hv.y), sscl[d + 2], sshf[d + 2]) + bflo(xv.y), 0.f);
    o.w = fmaxf(fmaf(bfhi(hv.y), sscl[d + 3], sshf[d + 3]) + bfhi(xv.y), 0.f);
    ((float4*)out)[i] = o;
}

extern "C" void kernel_launch(void* const* d_in, const int* in_sizes, int n_in,
                              void* d_out, int out_size, void* d_ws, size_t ws_size,
                              hipStream_t stream) {
    const float* x     = (const float*)d_in[0];
    const int*   eidx  = (const int*)d_in[1];
    const float* W_l   = (const float*)d_in[2];
    const float* W_r   = (const float*)d_in[4];
    const float* gamma = (const float*)d_in[5];
    const float* beta  = (const float*)d_in[6];

    const int D = in_sizes[3];            // 128
    const int N = in_sizes[0] / D;        // 100000
    const int E = in_sizes[1] / 2;        // 1600000

    const int* src = eidx;
    const int* dst = eidx + E;

    const int NBLK  = (N + 127) / 128;        // mfma blocks (782)
    const int Npad  = NBLK * 128;             // padded rows (100096)
    const int NP    = NBLK * 4;               // pstat rows
    const int NBUK  = (N + BSZ2 - 1) / BSZ2;  // buckets (391)
    const int M     = NBUK * SBLK;            // ghist cells (100096)
    const int NB2   = (M + 1023) / 1024;      // ghist-scan blocks
    const int chunk = (E + SBLK - 1) / SBLK;  // edges per sort block (6250)
    const int total4 = N * D128 / 4;          // float4s in x

    // workspace layout (byte cursor, 64B-aligned chunks)
    char* wp = (char*)d_ws;
    auto alloc = [&](size_t bytes) {
        char* p = wp;
        wp += (bytes + 63) & ~(size_t)63;
        return p;
    };
    float*    stats = (float*)   alloc(256 * 4);
    int*      offs  = (int*)     alloc((size_t)(N + 1) * 4);
    int*      csr   = (int*)     alloc((size_t)E * 4);        // reused as pstat
    unsigned* pairs = (unsigned*)alloc((size_t)E * 4);
    int*      ghist = (int*)     alloc((size_t)M * 4);
    int*      gsc   = (int*)     alloc((size_t)(M + 1) * 4);
    int*      bsum  = (int*)     alloc(1024 * 4);
    int*      ebsum = (int*)     alloc(1024 * 4);
    unsigned short* Bsw  = (unsigned short*)alloc(4096 * 16);
    unsigned short* xb   = (unsigned short*)alloc((size_t)N * D128 * 2);
    unsigned short* aggb = (unsigned short*)alloc((size_t)Npad * D128 * 2);
    unsigned short* h16  = (unsigned short*)alloc((size_t)N * D128 * 2);
    float* pstat = (float*)csr;                               // after gather

    float* outp = (float*)d_out;
    float invN = 1.0f / (float)N;

    hipMemsetAsync(stats, 0, 256 * sizeof(float), stream);

    prep_kernel<<<16, 256, 0, stream>>>(W_l, W_r, Bsw);

    // bucket hist (+ fused x->bf16) -> scan -> block-private scatter
    bhist_kernel<<<SBLK, 256, 0, stream>>>(dst, ghist, x, xb, E, chunk, NBUK, total4);
    partial_kernel<<<NB2, 256, 0, stream>>>(ghist, bsum, M);
    scan_bsum_kernel<<<1, 1024, 0, stream>>>(bsum, ebsum, NB2, gsc + M, E);
    scan_final_kernel<<<NB2, 256, 0, stream>>>(ghist, ebsum, gsc, M);
    bscatter_kernel<<<SBLK, 256, 0, stream>>>(src, dst, gsc, pairs, E, chunk, NBUK);

    // per-bucket CSR build (also writes offs)
    csrbuild_kernel<<<NBUK, 256, 0, stream>>>(pairs, gsc, csr, offs, N, NBUK, E);

    gather_kernel<<<Npad / 8, 256, 0, stream>>>(offs, csr, xb, aggb, N, Npad);

    mfma_kernel<<<NBLK, 256, 0, stream>>>(aggb, xb, Bsw, h16, pstat, N);

    statreduce_kernel<<<64, 256, 0, stream>>>(pstat, stats, NP);

    {
        long long t4 = (long long)N * D128 / 4;
        finalize_kernel<<<(int)((t4 + 255) / 256), 256, 0, stream>>>(
            h16, xb, stats, gamma, beta, outp, t4, invN);
    }
}

// Round 11
// 295.652 us; speedup vs baseline: 1.0488x; 1.0253x over previous
//
#include <hip/hip_runtime.h>
#include <hip/hip_bf16.h>

// ---------------------------------------------------------------------------
// ResidualSAGEBlock: block-private bucket sort -> CSR(+offs) -> bf16 gather ->
// MFMA bf16 dual GEMM (+in-kernel BN stats) -> finalize(BN+res+ReLU).
// N=100000, D=128, E=1600000.
// R2: CSR gather replaced float-atomic scatter: 3095->812us.
// R3: gemm LDS 48->32KB, 5 blocks/CU: 812->761us.
// R4: multi-block scan (was 230us single-CU): 761->546us.
// R5: split gather from GEMM; MFMA bf16 GEMM; fused BN stats: 546->493us.
// R6 FAILED: global-atomic bucket append (cross-XCD line sharing): 493->757us.
// R7: 3-pass block-private counting sort: 757->409us.
// R8: bf16 gather source; offs folded into csrbuild; packed pairs: 409->306us.
// R9 FAILED: cooperative grid.sync tail costs ~370us at 1563 blocks: 306->310.
// R10: bf16 h; bf16 residual; bnparam folded into finalize: 306->303us.
// R11: dispatch-count attack (12->9): stats zeroed in prep (no memset);
//      scan_bsum folded into scan_final (redundant per-block LDS scan);
//      statreduce+pstat replaced by in-mfma LDS reduce + atomicAdd;
//      gather unrolled to 8 edges/iter (4 loads in flight per lane).
// ---------------------------------------------------------------------------

#define D128 128
#define BSH2 8          // log2(nodes per bucket)
#define BSZ2 256        // nodes per bucket
#define MAXBUK 1024     // LDS bound for buckets (NBUK=391 actual)
#define SBLK 256        // sort blocks
#define CAP  5120       // csrbuild LDS capacity (mean 4096, +16 sigma)

typedef short bf16x8 __attribute__((ext_vector_type(8)));
typedef float f32x4  __attribute__((ext_vector_type(4)));

static __device__ __forceinline__ unsigned short f2bf(float f) {
    unsigned u = __builtin_bit_cast(unsigned, f);
    unsigned r = u + 0x7fffu + ((u >> 16) & 1u);   // round-to-nearest-even
    return (unsigned short)(r >> 16);
}
static __device__ __forceinline__ float bflo(unsigned u) {   // low bf16 -> f32
    return __builtin_bit_cast(float, u << 16);
}
static __device__ __forceinline__ float bfhi(unsigned u) {   // high bf16 -> f32
    return __builtin_bit_cast(float, u & 0xffff0000u);
}

// --- build swizzled bf16 B for MFMA + zero stats ---------------------------
// Bsw[t][c][lane][j] = Wcat[t*32 + (lane>>4)*8 + j][c*16 + (lane&15)]
// Wcat[k][d] = k<128 ? Wl[d][k] : Wr[d][k-128].
__global__ __launch_bounds__(256) void prep_kernel(
    const float* __restrict__ Wl, const float* __restrict__ Wr,
    unsigned short* __restrict__ Bsw, float* __restrict__ stats) {
    if (blockIdx.x == 0) stats[threadIdx.x] = 0.f;   // 256 floats
    int idx = blockIdx.x * 256 + threadIdx.x;   // 0..4095
    if (idx >= 4096) return;
    int l = idx & 63;
    int c = (idx >> 6) & 7;
    int t = idx >> 9;
    int d = c * 16 + (l & 15);
    int kbase = t * 32 + (l >> 4) * 8;
    unsigned short o[8];
#pragma unroll
    for (int j = 0; j < 8; ++j) {
        int k = kbase + j;
        float v = (k < 128) ? Wl[d * 128 + k] : Wr[d * 128 + (k - 128)];
        o[j] = f2bf(v);
    }
    *(uint4*)(Bsw + (size_t)idx * 8) = *(const uint4*)o;
}

// --- sort pass 1: per-block bucket histogram + fused x->bf16 conversion ----
__global__ __launch_bounds__(256) void bhist_kernel(
    const int* __restrict__ dst, int* __restrict__ ghist,
    const float* __restrict__ x, unsigned short* __restrict__ xb,
    int E, int chunk, int NBUK, int total4) {
    __shared__ int lh[MAXBUK];
    int tid = threadIdx.x;
    int b   = blockIdx.x;
    for (int i = tid; i < NBUK; i += 256) lh[i] = 0;
    __syncthreads();
    int beg = b * chunk;
    int end = min(beg + chunk, E);
    for (int i = beg + tid; i < end; i += 256)
        atomicAdd(&lh[dst[i] >> BSH2], 1);
    __syncthreads();
    for (int i = tid; i < NBUK; i += 256) ghist[i * SBLK + b] = lh[i];
    // fused streaming conversion x (fp32) -> xb (bf16)
    for (int i = b * 256 + tid; i < total4; i += 256 * SBLK) {
        float4 v = ((const float4*)x)[i];
        uint2 o;
        o.x = (unsigned)f2bf(v.x) | ((unsigned)f2bf(v.y) << 16);
        o.y = (unsigned)f2bf(v.z) | ((unsigned)f2bf(v.w) << 16);
        ((uint2*)xb)[i] = o;
    }
}

// --- scan stage 1: per-block (1024 elems) partial sums ---------------------
__global__ __launch_bounds__(256) void partial_kernel(const int* __restrict__ deg,
                                                      int* __restrict__ bsum, int N) {
    int tid  = threadIdx.x;
    int base = blockIdx.x * 1024 + tid * 4;
    int s = 0;
    if (base + 3 < N) {
        int4 v = *(const int4*)(deg + base);
        s = v.x + v.y + v.z + v.w;
    } else {
        for (int i = base; i < N; ++i) s += deg[i];
    }
    __shared__ int red[256];
    red[tid] = s;
    __syncthreads();
    for (int off = 128; off > 0; off >>= 1) {
        if (tid < off) red[tid] += red[tid + off];
        __syncthreads();
    }
    if (tid == 0) bsum[blockIdx.x] = red[0];
}

// --- scan stage 2 (final): per-block scan + redundant LDS scan of bsum -----
// Each block scans bsum[0..NB2) itself (NB2 <= 256) -> no scan_bsum dispatch.
__global__ __launch_bounds__(256) void scan_final_kernel(
    const int* __restrict__ deg, const int* __restrict__ bsum,
    int* __restrict__ offs, int N, int NB2) {
    __shared__ int sb[2][256];
    int tid = threadIdx.x;
    // inclusive scan of bsum over 256 slots (zero-padded)
    int bv = (tid < NB2) ? bsum[tid] : 0;
    sb[0][tid] = bv;
    __syncthreads();
    int bpi = 0;
    for (int off = 1; off < 256; off <<= 1) {
        int u = sb[bpi][tid];
        if (tid >= off) u += sb[bpi][tid - off];
        sb[bpi ^ 1][tid] = u;
        __syncthreads();
        bpi ^= 1;
    }
    int ebsum = (blockIdx.x > 0) ? sb[bpi][blockIdx.x - 1] : 0;
    __syncthreads();

    int base = blockIdx.x * 1024 + tid * 4;
    int d0 = 0, d1 = 0, d2 = 0, d3 = 0;
    if (base + 3 < N) {
        int4 v = *(const int4*)(deg + base);
        d0 = v.x; d1 = v.y; d2 = v.z; d3 = v.w;
    } else {
        if (base     < N) d0 = deg[base];
        if (base + 1 < N) d1 = deg[base + 1];
        if (base + 2 < N) d2 = deg[base + 2];
        if (base + 3 < N) d3 = deg[base + 3];
    }
    int s = d0 + d1 + d2 + d3;
    sb[0][tid] = s;
    __syncthreads();
    int pi = 0;
    for (int off = 1; off < 256; off <<= 1) {
        int u = sb[pi][tid];
        if (tid >= off) u += sb[pi][tid - off];
        sb[pi ^ 1][tid] = u;
        __syncthreads();
        pi ^= 1;
    }
    int pre = sb[pi][tid] - s + ebsum;
    if (base + 3 < N) {
        int4 o = make_int4(pre, pre + d0, pre + d0 + d1, pre + d0 + d1 + d2);
        *(int4*)(offs + base) = o;
    } else {
        int p = pre;
        if (base     < N) { offs[base]     = p; p += d0; }
        if (base + 1 < N) { offs[base + 1] = p; p += d1; }
        if (base + 2 < N) { offs[base + 2] = p; p += d2; }
        if (base + 3 < N) { offs[base + 3] = p; }
    }
}

// --- sort pass 2: scatter packed (src<<8 | dst&255) into private ranges ----
__global__ __launch_bounds__(256) void bscatter_kernel(
    const int* __restrict__ src, const int* __restrict__ dst,
    const int* __restrict__ gsc, unsigned* __restrict__ pairs,
    int E, int chunk, int NBUK) {
    __shared__ int lcur[MAXBUK];
    int tid = threadIdx.x;
    int b   = blockIdx.x;
    for (int i = tid; i < NBUK; i += 256) lcur[i] = gsc[i * SBLK + b];
    __syncthreads();
    int beg = b * chunk;
    int end = min(beg + chunk, E);
    for (int i = beg + tid; i < end; i += 256) {
        int d = dst[i];
        int s = src[i];
        int pos = atomicAdd(&lcur[d >> BSH2], 1);
        pairs[pos] = ((unsigned)s << 8) | (unsigned)(d & 255);
    }
}

// --- per-bucket: local node histogram + scan -> offs; LDS sort -> csr ------
__global__ __launch_bounds__(256) void csrbuild_kernel(
    const unsigned* __restrict__ pairs, const int* __restrict__ gsc,
    int* __restrict__ csr, int* __restrict__ offs, int N, int NBUK, int E) {
    __shared__ int lcnt[BSZ2];
    __shared__ int sbuf[2][BSZ2];
    __shared__ int lcsr[CAP];
    int b   = blockIdx.x;
    int tid = threadIdx.x;
    int nlo = b << BSH2;
    int base = gsc[(size_t)b * SBLK];                       // bucket start
    int end  = (b + 1 < NBUK) ? gsc[(size_t)(b + 1) * SBLK] : E;
    int len  = end - base;
    lcnt[tid] = 0;
    __syncthreads();
    for (int i = tid; i < len; i += 256)
        atomicAdd(&lcnt[pairs[base + i] & 255u], 1);
    __syncthreads();
    int c = lcnt[tid];
    sbuf[0][tid] = c;
    __syncthreads();
    int pi = 0;
    for (int off = 1; off < 256; off <<= 1) {
        int u = sbuf[pi][tid];
        if (tid >= off) u += sbuf[pi][tid - off];
        sbuf[pi ^ 1][tid] = u;
        __syncthreads();
        pi ^= 1;
    }
    int pre = sbuf[pi][tid] - c;
    if (nlo + tid <= N) offs[nlo + tid] = base + pre;       // covers offs[N]=E
    lcnt[tid] = pre;                                        // reuse as cursor
    __syncthreads();
    if (len <= CAP) {
        for (int i = tid; i < len; i += 256) {
            unsigned p = pairs[base + i];
            int pos = atomicAdd(&lcnt[p & 255u], 1);
            lcsr[pos] = (int)(p >> 8);
        }
        __syncthreads();
        for (int i = tid; i < len; i += 256) csr[base + i] = lcsr[i];
    } else {
        for (int i = tid; i < len; i += 256) {
            unsigned p = pairs[base + i];
            int pos = atomicAdd(&lcnt[p & 255u], 1);
            csr[base + pos] = (int)(p >> 8);
        }
    }
}

// --- gather-mean from bf16 xb: aggb[n][:] = mean of xb[src] rows -----------
// 8 nodes/block; 32-lane group per node; half=(lane>>4) takes alternate edges;
// fl=lane&15 owns 8 features (16B uint4). 8 edges/iter = 4 loads in flight.
__global__ __launch_bounds__(256) void gather_kernel(
    const int* __restrict__ offs, const int* __restrict__ csr,
    const unsigned short* __restrict__ xb, unsigned short* __restrict__ aggb,
    int N, int Npad) {
    int tid  = threadIdx.x;
    int l    = tid & 31;
    int half = l >> 4;
    int fl   = l & 15;
    int n    = blockIdx.x * 8 + (tid >> 5);
    if (n >= Npad) return;
    float f[8] = {0.f, 0.f, 0.f, 0.f, 0.f, 0.f, 0.f, 0.f};
    float g[8] = {0.f, 0.f, 0.f, 0.f, 0.f, 0.f, 0.f, 0.f};
    float inv = 0.f;
    if (n < N) {
        int beg = offs[n], end = offs[n + 1];
        int deg = end - beg;
        int k = beg;
        for (; k + 8 <= end; k += 8) {
            int s0 = csr[k + half];
            int s1 = csr[k + 2 + half];
            int s2 = csr[k + 4 + half];
            int s3 = csr[k + 6 + half];
            uint4 v0 = *(const uint4*)(xb + (size_t)s0 * D128 + fl * 8);
            uint4 v1 = *(const uint4*)(xb + (size_t)s1 * D128 + fl * 8);
            uint4 v2 = *(const uint4*)(xb + (size_t)s2 * D128 + fl * 8);
            uint4 v3 = *(const uint4*)(xb + (size_t)s3 * D128 + fl * 8);
            f[0] += bflo(v0.x); f[1] += bfhi(v0.x);
            f[2] += bflo(v0.y); f[3] += bfhi(v0.y);
            f[4] += bflo(v0.z); f[5] += bfhi(v0.z);
            f[6] += bflo(v0.w); f[7] += bfhi(v0.w);
            g[0] += bflo(v1.x); g[1] += bfhi(v1.x);
            g[2] += bflo(v1.y); g[3] += bfhi(v1.y);
            g[4] += bflo(v1.z); g[5] += bfhi(v1.z);
            g[6] += bflo(v1.w); g[7] += bfhi(v1.w);
            f[0] += bflo(v2.x); f[1] += bfhi(v2.x);
            f[2] += bflo(v2.y); f[3] += bfhi(v2.y);
            f[4] += bflo(v2.z); f[5] += bfhi(v2.z);
            f[6] += bflo(v2.w); f[7] += bfhi(v2.w);
            g[0] += bflo(v3.x); g[1] += bfhi(v3.x);
            g[2] += bflo(v3.y); g[3] += bfhi(v3.y);
            g[4] += bflo(v3.z); g[5] += bfhi(v3.z);
            g[6] += bflo(v3.w); g[7] += bfhi(v3.w);
        }
        if (end - k >= 4) {
            int s0 = csr[k + half];
            int s1 = csr[k + 2 + half];
            uint4 v0 = *(const uint4*)(xb + (size_t)s0 * D128 + fl * 8);
            uint4 v1 = *(const uint4*)(xb + (size_t)s1 * D128 + fl * 8);
            f[0] += bflo(v0.x); f[1] += bfhi(v0.x);
            f[2] += bflo(v0.y); f[3] += bfhi(v0.y);
            f[4] += bflo(v0.z); f[5] += bfhi(v0.z);
            f[6] += bflo(v0.w); f[7] += bfhi(v0.w);
            g[0] += bflo(v1.x); g[1] += bfhi(v1.x);
            g[2] += bflo(v1.y); g[3] += bfhi(v1.y);
            g[4] += bflo(v1.z); g[5] += bfhi(v1.z);
            g[6] += bflo(v1.w); g[7] += bfhi(v1.w);
            k += 4;
        }
        if (end - k >= 2) {
            int s0 = csr[k + half];
            uint4 v0 = *(const uint4*)(xb + (size_t)s0 * D128 + fl * 8);
            f[0] += bflo(v0.x); f[1] += bfhi(v0.x);
            f[2] += bflo(v0.y); f[3] += bfhi(v0.y);
            f[4] += bflo(v0.z); f[5] += bfhi(v0.z);
            f[6] += bflo(v0.w); f[7] += bfhi(v0.w);
            k += 2;
        }
        if (k < end && half == 0) {
            int s0 = csr[k];
            uint4 v0 = *(const uint4*)(xb + (size_t)s0 * D128 + fl * 8);
            f[0] += bflo(v0.x); f[1] += bfhi(v0.x);
            f[2] += bflo(v0.y); f[3] += bfhi(v0.y);
            f[4] += bflo(v0.z); f[5] += bfhi(v0.z);
            f[6] += bflo(v0.w); f[7] += bfhi(v0.w);
        }
        if (deg > 0) inv = 1.0f / (float)deg;
    }
#pragma unroll
    for (int j = 0; j < 8; ++j) {
        f[j] += g[j];
        f[j] += __shfl_xor(f[j], 16, 64);   // combine halves (stays in group)
    }
    if (half == 0) {
        uint4 o;
        o.x = (unsigned)f2bf(f[0] * inv) | ((unsigned)f2bf(f[1] * inv) << 16);
        o.y = (unsigned)f2bf(f[2] * inv) | ((unsigned)f2bf(f[3] * inv) << 16);
        o.z = (unsigned)f2bf(f[4] * inv) | ((unsigned)f2bf(f[5] * inv) << 16);
        o.w = (unsigned)f2bf(f[6] * inv) | ((unsigned)f2bf(f[7] * inv) << 16);
        *(uint4*)(aggb + (size_t)n * D128 + fl * 8) = o;
    }
}

// --- MFMA dual GEMM -> bf16 h + in-kernel BN stats (LDS reduce + atomic) ---
// K=256: ksteps 0-3 read aggb, 4-7 read xb. No b_l (cancelled by BN).
__global__ __launch_bounds__(256) void mfma_kernel(
    const unsigned short* __restrict__ aggb, const unsigned short* __restrict__ xb,
    const unsigned short* __restrict__ Bsw,
    unsigned short* __restrict__ h16, float* __restrict__ stats, int N) {
    __shared__ float red[4][256];
    int tid  = threadIdx.x;
    int w    = tid >> 6;
    int lane = tid & 63;
    int lc   = lane & 15;    // tile col
    int lq   = lane >> 4;    // quarter
    int rowBase = blockIdx.x * 128 + w * 32;

    f32x4 acc[2][8];
#pragma unroll
    for (int c = 0; c < 8; ++c) {
        f32x4 z = {0.f, 0.f, 0.f, 0.f};
        acc[0][c] = z;
        acc[1][c] = z;
    }
    int r0  = rowBase + lc;
    int r1  = rowBase + 16 + lc;
    int r0c = min(r0, N - 1);
    int r1c = min(r1, N - 1);
    for (int t = 0; t < 8; ++t) {
        const unsigned short* p0;
        const unsigned short* p1;
        if (t < 4) {
            int off = t * 32 + lq * 8;
            p0 = aggb + (size_t)r0 * D128 + off;
            p1 = aggb + (size_t)r1 * D128 + off;
        } else {
            int off = (t - 4) * 32 + lq * 8;
            p0 = xb + (size_t)r0c * D128 + off;
            p1 = xb + (size_t)r1c * D128 + off;
        }
        bf16x8 a0 = *(const bf16x8*)p0;
        bf16x8 a1 = *(const bf16x8*)p1;
#pragma unroll
        for (int c = 0; c < 8; ++c) {
            bf16x8 bf = *(const bf16x8*)(Bsw + ((size_t)((t * 8 + c) * 64 + lane)) * 8);
            acc[0][c] = __builtin_amdgcn_mfma_f32_16x16x32_bf16(a0, bf, acc[0][c], 0, 0, 0);
            acc[1][c] = __builtin_amdgcn_mfma_f32_16x16x32_bf16(a1, bf, acc[1][c], 0, 0, 0);
        }
    }
    float s[8], ss[8];
#pragma unroll
    for (int c = 0; c < 8; ++c) { s[c] = 0.f; ss[c] = 0.f; }
#pragma unroll
    for (int rh = 0; rh < 2; ++rh) {
#pragma unroll
        for (int reg = 0; reg < 4; ++reg) {
            int row = rowBase + rh * 16 + lq * 4 + reg;   // C-layout row
            if (row < N) {
#pragma unroll
                for (int c = 0; c < 8; ++c) {
                    float v = acc[rh][c][reg];
                    h16[(size_t)row * D128 + c * 16 + lc] = f2bf(v);
                    s[c]  += v;
                    ss[c] += v * v;
                }
            }
        }
    }
#pragma unroll
    for (int c = 0; c < 8; ++c) {
        s[c]  += __shfl_xor(s[c], 16, 64);
        s[c]  += __shfl_xor(s[c], 32, 64);
        ss[c] += __shfl_xor(ss[c], 16, 64);
        ss[c] += __shfl_xor(ss[c], 32, 64);
    }
    if (lq == 0) {
#pragma unroll
        for (int c = 0; c < 8; ++c) {
            red[w][c * 16 + lc]       = s[c];
            red[w][128 + c * 16 + lc] = ss[c];
        }
    }
    __syncthreads();
    float tot = red[0][tid] + red[1][tid] + red[2][tid] + red[3][tid];
    atomicAdd(&stats[tid], tot);
}

// --- finalize: BN params in LDS, out = relu(h16*scl + shf + xb) ------------
__global__ __launch_bounds__(256) void finalize_kernel(
    const unsigned short* __restrict__ h16, const unsigned short* __restrict__ xb,
    const float* __restrict__ stats, const float* __restrict__ gamma,
    const float* __restrict__ beta, float* __restrict__ out,
    long long total4, float invN) {
    __shared__ float sscl[D128];
    __shared__ float sshf[D128];
    int tid = threadIdx.x;
    if (tid < D128) {
        float mean = stats[tid] * invN;
        float var  = stats[D128 + tid] * invN - mean * mean;
        float istd = rsqrtf(var + 1e-5f);
        float sc   = gamma[tid] * istd;
        sscl[tid] = sc;
        sshf[tid] = beta[tid] - mean * sc;
    }
    __syncthreads();
    long long i = (long long)blockIdx.x * 256 + tid;
    if (i >= total4) return;
    int d = (int)((i * 4) & 127);
    uint2 hv = ((const uint2*)h16)[i];
    uint2 xv = ((const uint2*)xb)[i];
    float4 o;
    o.x = fmaxf(fmaf(bflo(hv.x), sscl[d],     sshf[d])     + bflo(xv.x), 0.f);
    o.y = fmaxf(fmaf(bfhi(hv.x), sscl[d + 1], sshf[d + 1]) + bfhi(xv.x), 0.f);
    o.z = fmaxf(fmaf(bflo(hv.y), sscl[d + 2], sshf[d + 2]) + bflo(xv.y), 0.f);
    o.w = fmaxf(fmaf(bfhi(hv.y), sscl[d + 3], sshf[d + 3]) + bfhi(xv.y), 0.f);
    ((float4*)out)[i] = o;
}

extern "C" void kernel_launch(void* const* d_in, const int* in_sizes, int n_in,
                              void* d_out, int out_size, void* d_ws, size_t ws_size,
                              hipStream_t stream) {
    const float* x     = (const float*)d_in[0];
    const int*   eidx  = (const int*)d_in[1];
    const float* W_l   = (const float*)d_in[2];
    const float* W_r   = (const float*)d_in[4];
    const float* gamma = (const float*)d_in[5];
    const float* beta  = (const float*)d_in[6];

    const int D = in_sizes[3];            // 128
    const int N = in_sizes[0] / D;        // 100000
    const int E = in_sizes[1] / 2;        // 1600000

    const int* src = eidx;
    const int* dst = eidx + E;

    const int NBLK  = (N + 127) / 128;        // mfma blocks (782)
    const int Npad  = NBLK * 128;             // padded rows (100096)
    const int NBUK  = (N + BSZ2 - 1) / BSZ2;  // buckets (391)
    const int M     = NBUK * SBLK;            // ghist cells (100096)
    const int NB2   = (M + 1023) / 1024;      // ghist-scan blocks (98, <=256)
    const int chunk = (E + SBLK - 1) / SBLK;  // edges per sort block (6250)
    const int total4 = N * D128 / 4;          // float4s in x

    // workspace layout (byte cursor, 64B-aligned chunks)
    char* wp = (char*)d_ws;
    auto alloc = [&](size_t bytes) {
        char* p = wp;
        wp += (bytes + 63) & ~(size_t)63;
        return p;
    };
    float*    stats = (float*)   alloc(256 * 4);
    int*      offs  = (int*)     alloc((size_t)(N + 1) * 4);
    int*      csr   = (int*)     alloc((size_t)E * 4);
    unsigned* pairs = (unsigned*)alloc((size_t)E * 4);
    int*      ghist = (int*)     alloc((size_t)M * 4);
    int*      gsc   = (int*)     alloc((size_t)(M + 1) * 4);
    int*      bsum  = (int*)     alloc(1024 * 4);
    unsigned short* Bsw  = (unsigned short*)alloc(4096 * 16);
    unsigned short* xb   = (unsigned short*)alloc((size_t)N * D128 * 2);
    unsigned short* aggb = (unsigned short*)alloc((size_t)Npad * D128 * 2);
    unsigned short* h16  = (unsigned short*)alloc((size_t)N * D128 * 2);

    float* outp = (float*)d_out;
    float invN = 1.0f / (float)N;

    prep_kernel<<<16, 256, 0, stream>>>(W_l, W_r, Bsw, stats);

    // bucket hist (+ fused x->bf16) -> scan -> block-private scatter
    bhist_kernel<<<SBLK, 256, 0, stream>>>(dst, ghist, x, xb, E, chunk, NBUK, total4);
    partial_kernel<<<NB2, 256, 0, stream>>>(ghist, bsum, M);
    scan_final_kernel<<<NB2, 256, 0, stream>>>(ghist, bsum, gsc, M, NB2);
    bscatter_kernel<<<SBLK, 256, 0, stream>>>(src, dst, gsc, pairs, E, chunk, NBUK);

    // per-bucket CSR build (also writes offs)
    csrbuild_kernel<<<NBUK, 256, 0, stream>>>(pairs, gsc, csr, offs, N, NBUK, E);

    gather_kernel<<<Npad / 8, 256, 0, stream>>>(offs, csr, xb, aggb, N, Npad);

    mfma_kernel<<<NBLK, 256, 0, stream>>>(aggb, xb, Bsw, h16, stats, N);

    {
        long long t4 = (long long)N * D128 / 4;
        finalize_kernel<<<(int)((t4 + 255) / 256), 256, 0, stream>>>(
            h16, xb, stats, gamma, beta, outp, t4, invN);
    }
}

// Round 12
// 287.710 us; speedup vs baseline: 1.0778x; 1.0276x over previous
//
#include <hip/hip_runtime.h>
#include <hip/hip_bf16.h>

// ---------------------------------------------------------------------------
// ResidualSAGEBlock: block-private bucket sort -> CSR(+offs) -> bf16 gather ->
// MFMA bf16 dual GEMM (+in-kernel BN stats) -> finalize(BN+res+ReLU).
// N=100000, D=128, E=1600000.
// R2: CSR gather replaced float-atomic scatter: 3095->812us.
// R3: gemm LDS 48->32KB, 5 blocks/CU: 812->761us.
// R4: multi-block scan (was 230us single-CU): 761->546us.
// R5: split gather from GEMM; MFMA bf16 GEMM; fused BN stats: 546->493us.
// R6 FAILED: global-atomic bucket append (cross-XCD line sharing): 493->757us.
// R7: 3-pass block-private counting sort: 757->409us.
// R8: bf16 gather source; offs folded into csrbuild; packed pairs: 409->306us.
// R9 FAILED: cooperative grid.sync tail costs ~370us at 1563 blocks: 306->310.
// R10: bf16 h; bf16 residual; bnparam folded into finalize: 306->303us.
// R11: 12->9 dispatches; in-mfma stat atomics: 303->296us BUT mfma 30->64us
//      (782 blocks x 256 lanes atomicAdd into 16 lines = same-line serialize).
// R12: 32-way replicated stats (block b -> replica b&31): contention/address
//      782->25. finalize sums replicas. prep zeroes all 8192 floats.
// ---------------------------------------------------------------------------

#define D128 128
#define BSH2 8          // log2(nodes per bucket)
#define BSZ2 256        // nodes per bucket
#define MAXBUK 1024     // LDS bound for buckets (NBUK=391 actual)
#define SBLK 256        // sort blocks
#define CAP  5120       // csrbuild LDS capacity (mean 4096, +16 sigma)
#define SREP 32         // stat replicas

typedef short bf16x8 __attribute__((ext_vector_type(8)));
typedef float f32x4  __attribute__((ext_vector_type(4)));

static __device__ __forceinline__ unsigned short f2bf(float f) {
    unsigned u = __builtin_bit_cast(unsigned, f);
    unsigned r = u + 0x7fffu + ((u >> 16) & 1u);   // round-to-nearest-even
    return (unsigned short)(r >> 16);
}
static __device__ __forceinline__ float bflo(unsigned u) {   // low bf16 -> f32
    return __builtin_bit_cast(float, u << 16);
}
static __device__ __forceinline__ float bfhi(unsigned u) {   // high bf16 -> f32
    return __builtin_bit_cast(float, u & 0xffff0000u);
}

// --- build swizzled bf16 B for MFMA + zero replicated stats ----------------
// Bsw[t][c][lane][j] = Wcat[t*32 + (lane>>4)*8 + j][c*16 + (lane&15)]
// Wcat[k][d] = k<128 ? Wl[d][k] : Wr[d][k-128].
__global__ __launch_bounds__(256) void prep_kernel(
    const float* __restrict__ Wl, const float* __restrict__ Wr,
    unsigned short* __restrict__ Bsw, float* __restrict__ stats) {
    int idx = blockIdx.x * 256 + threadIdx.x;   // 0..4095
    stats[idx] = 0.f;                           // 2 x 4096 = SREP*256 floats
    stats[idx + 4096] = 0.f;
    if (idx >= 4096) return;
    int l = idx & 63;
    int c = (idx >> 6) & 7;
    int t = idx >> 9;
    int d = c * 16 + (l & 15);
    int kbase = t * 32 + (l >> 4) * 8;
    unsigned short o[8];
#pragma unroll
    for (int j = 0; j < 8; ++j) {
        int k = kbase + j;
        float v = (k < 128) ? Wl[d * 128 + k] : Wr[d * 128 + (k - 128)];
        o[j] = f2bf(v);
    }
    *(uint4*)(Bsw + (size_t)idx * 8) = *(const uint4*)o;
}

// --- sort pass 1: per-block bucket histogram + fused x->bf16 conversion ----
__global__ __launch_bounds__(256) void bhist_kernel(
    const int* __restrict__ dst, int* __restrict__ ghist,
    const float* __restrict__ x, unsigned short* __restrict__ xb,
    int E, int chunk, int NBUK, int total4) {
    __shared__ int lh[MAXBUK];
    int tid = threadIdx.x;
    int b   = blockIdx.x;
    for (int i = tid; i < NBUK; i += 256) lh[i] = 0;
    __syncthreads();
    int beg = b * chunk;
    int end = min(beg + chunk, E);
    for (int i = beg + tid; i < end; i += 256)
        atomicAdd(&lh[dst[i] >> BSH2], 1);
    __syncthreads();
    for (int i = tid; i < NBUK; i += 256) ghist[i * SBLK + b] = lh[i];
    // fused streaming conversion x (fp32) -> xb (bf16)
    for (int i = b * 256 + tid; i < total4; i += 256 * SBLK) {
        float4 v = ((const float4*)x)[i];
        uint2 o;
        o.x = (unsigned)f2bf(v.x) | ((unsigned)f2bf(v.y) << 16);
        o.y = (unsigned)f2bf(v.z) | ((unsigned)f2bf(v.w) << 16);
        ((uint2*)xb)[i] = o;
    }
}

// --- scan stage 1: per-block (1024 elems) partial sums ---------------------
__global__ __launch_bounds__(256) void partial_kernel(const int* __restrict__ deg,
                                                      int* __restrict__ bsum, int N) {
    int tid  = threadIdx.x;
    int base = blockIdx.x * 1024 + tid * 4;
    int s = 0;
    if (base + 3 < N) {
        int4 v = *(const int4*)(deg + base);
        s = v.x + v.y + v.z + v.w;
    } else {
        for (int i = base; i < N; ++i) s += deg[i];
    }
    __shared__ int red[256];
    red[tid] = s;
    __syncthreads();
    for (int off = 128; off > 0; off >>= 1) {
        if (tid < off) red[tid] += red[tid + off];
        __syncthreads();
    }
    if (tid == 0) bsum[blockIdx.x] = red[0];
}

// --- scan stage 2 (final): per-block scan + redundant LDS scan of bsum -----
__global__ __launch_bounds__(256) void scan_final_kernel(
    const int* __restrict__ deg, const int* __restrict__ bsum,
    int* __restrict__ offs, int N, int NB2) {
    __shared__ int sb[2][256];
    int tid = threadIdx.x;
    int bv = (tid < NB2) ? bsum[tid] : 0;
    sb[0][tid] = bv;
    __syncthreads();
    int bpi = 0;
    for (int off = 1; off < 256; off <<= 1) {
        int u = sb[bpi][tid];
        if (tid >= off) u += sb[bpi][tid - off];
        sb[bpi ^ 1][tid] = u;
        __syncthreads();
        bpi ^= 1;
    }
    int ebsum = (blockIdx.x > 0) ? sb[bpi][blockIdx.x - 1] : 0;
    __syncthreads();

    int base = blockIdx.x * 1024 + tid * 4;
    int d0 = 0, d1 = 0, d2 = 0, d3 = 0;
    if (base + 3 < N) {
        int4 v = *(const int4*)(deg + base);
        d0 = v.x; d1 = v.y; d2 = v.z; d3 = v.w;
    } else {
        if (base     < N) d0 = deg[base];
        if (base + 1 < N) d1 = deg[base + 1];
        if (base + 2 < N) d2 = deg[base + 2];
        if (base + 3 < N) d3 = deg[base + 3];
    }
    int s = d0 + d1 + d2 + d3;
    sb[0][tid] = s;
    __syncthreads();
    int pi = 0;
    for (int off = 1; off < 256; off <<= 1) {
        int u = sb[pi][tid];
        if (tid >= off) u += sb[pi][tid - off];
        sb[pi ^ 1][tid] = u;
        __syncthreads();
        pi ^= 1;
    }
    int pre = sb[pi][tid] - s + ebsum;
    if (base + 3 < N) {
        int4 o = make_int4(pre, pre + d0, pre + d0 + d1, pre + d0 + d1 + d2);
        *(int4*)(offs + base) = o;
    } else {
        int p = pre;
        if (base     < N) { offs[base]     = p; p += d0; }
        if (base + 1 < N) { offs[base + 1] = p; p += d1; }
        if (base + 2 < N) { offs[base + 2] = p; p += d2; }
        if (base + 3 < N) { offs[base + 3] = p; }
    }
}

// --- sort pass 2: scatter packed (src<<8 | dst&255) into private ranges ----
__global__ __launch_bounds__(256) void bscatter_kernel(
    const int* __restrict__ src, const int* __restrict__ dst,
    const int* __restrict__ gsc, unsigned* __restrict__ pairs,
    int E, int chunk, int NBUK) {
    __shared__ int lcur[MAXBUK];
    int tid = threadIdx.x;
    int b   = blockIdx.x;
    for (int i = tid; i < NBUK; i += 256) lcur[i] = gsc[i * SBLK + b];
    __syncthreads();
    int beg = b * chunk;
    int end = min(beg + chunk, E);
    for (int i = beg + tid; i < end; i += 256) {
        int d = dst[i];
        int s = src[i];
        int pos = atomicAdd(&lcur[d >> BSH2], 1);
        pairs[pos] = ((unsigned)s << 8) | (unsigned)(d & 255);
    }
}

// --- per-bucket: local node histogram + scan -> offs; LDS sort -> csr ------
__global__ __launch_bounds__(256) void csrbuild_kernel(
    const unsigned* __restrict__ pairs, const int* __restrict__ gsc,
    int* __restrict__ csr, int* __restrict__ offs, int N, int NBUK, int E) {
    __shared__ int lcnt[BSZ2];
    __shared__ int sbuf[2][BSZ2];
    __shared__ int lcsr[CAP];
    int b   = blockIdx.x;
    int tid = threadIdx.x;
    int nlo = b << BSH2;
    int base = gsc[(size_t)b * SBLK];                       // bucket start
    int end  = (b + 1 < NBUK) ? gsc[(size_t)(b + 1) * SBLK] : E;
    int len  = end - base;
    lcnt[tid] = 0;
    __syncthreads();
    for (int i = tid; i < len; i += 256)
        atomicAdd(&lcnt[pairs[base + i] & 255u], 1);
    __syncthreads();
    int c = lcnt[tid];
    sbuf[0][tid] = c;
    __syncthreads();
    int pi = 0;
    for (int off = 1; off < 256; off <<= 1) {
        int u = sbuf[pi][tid];
        if (tid >= off) u += sbuf[pi][tid - off];
        sbuf[pi ^ 1][tid] = u;
        __syncthreads();
        pi ^= 1;
    }
    int pre = sbuf[pi][tid] - c;
    if (nlo + tid <= N) offs[nlo + tid] = base + pre;       // covers offs[N]=E
    lcnt[tid] = pre;                                        // reuse as cursor
    __syncthreads();
    if (len <= CAP) {
        for (int i = tid; i < len; i += 256) {
            unsigned p = pairs[base + i];
            int pos = atomicAdd(&lcnt[p & 255u], 1);
            lcsr[pos] = (int)(p >> 8);
        }
        __syncthreads();
        for (int i = tid; i < len; i += 256) csr[base + i] = lcsr[i];
    } else {
        for (int i = tid; i < len; i += 256) {
            unsigned p = pairs[base + i];
            int pos = atomicAdd(&lcnt[p & 255u], 1);
            csr[base + pos] = (int)(p >> 8);
        }
    }
}

// --- gather-mean from bf16 xb: aggb[n][:] = mean of xb[src] rows -----------
__global__ __launch_bounds__(256) void gather_kernel(
    const int* __restrict__ offs, const int* __restrict__ csr,
    const unsigned short* __restrict__ xb, unsigned short* __restrict__ aggb,
    int N, int Npad) {
    int tid  = threadIdx.x;
    int l    = tid & 31;
    int half = l >> 4;
    int fl   = l & 15;
    int n    = blockIdx.x * 8 + (tid >> 5);
    if (n >= Npad) return;
    float f[8] = {0.f, 0.f, 0.f, 0.f, 0.f, 0.f, 0.f, 0.f};
    float g[8] = {0.f, 0.f, 0.f, 0.f, 0.f, 0.f, 0.f, 0.f};
    float inv = 0.f;
    if (n < N) {
        int beg = offs[n], end = offs[n + 1];
        int deg = end - beg;
        int k = beg;
        for (; k + 8 <= end; k += 8) {
            int s0 = csr[k + half];
            int s1 = csr[k + 2 + half];
            int s2 = csr[k + 4 + half];
            int s3 = csr[k + 6 + half];
            uint4 v0 = *(const uint4*)(xb + (size_t)s0 * D128 + fl * 8);
            uint4 v1 = *(const uint4*)(xb + (size_t)s1 * D128 + fl * 8);
            uint4 v2 = *(const uint4*)(xb + (size_t)s2 * D128 + fl * 8);
            uint4 v3 = *(const uint4*)(xb + (size_t)s3 * D128 + fl * 8);
            f[0] += bflo(v0.x); f[1] += bfhi(v0.x);
            f[2] += bflo(v0.y); f[3] += bfhi(v0.y);
            f[4] += bflo(v0.z); f[5] += bfhi(v0.z);
            f[6] += bflo(v0.w); f[7] += bfhi(v0.w);
            g[0] += bflo(v1.x); g[1] += bfhi(v1.x);
            g[2] += bflo(v1.y); g[3] += bfhi(v1.y);
            g[4] += bflo(v1.z); g[5] += bfhi(v1.z);
            g[6] += bflo(v1.w); g[7] += bfhi(v1.w);
            f[0] += bflo(v2.x); f[1] += bfhi(v2.x);
            f[2] += bflo(v2.y); f[3] += bfhi(v2.y);
            f[4] += bflo(v2.z); f[5] += bfhi(v2.z);
            f[6] += bflo(v2.w); f[7] += bfhi(v2.w);
            g[0] += bflo(v3.x); g[1] += bfhi(v3.x);
            g[2] += bflo(v3.y); g[3] += bfhi(v3.y);
            g[4] += bflo(v3.z); g[5] += bfhi(v3.z);
            g[6] += bflo(v3.w); g[7] += bfhi(v3.w);
        }
        if (end - k >= 4) {
            int s0 = csr[k + half];
            int s1 = csr[k + 2 + half];
            uint4 v0 = *(const uint4*)(xb + (size_t)s0 * D128 + fl * 8);
            uint4 v1 = *(const uint4*)(xb + (size_t)s1 * D128 + fl * 8);
            f[0] += bflo(v0.x); f[1] += bfhi(v0.x);
            f[2] += bflo(v0.y); f[3] += bfhi(v0.y);
            f[4] += bflo(v0.z); f[5] += bfhi(v0.z);
            f[6] += bflo(v0.w); f[7] += bfhi(v0.w);
            g[0] += bflo(v1.x); g[1] += bfhi(v1.x);
            g[2] += bflo(v1.y); g[3] += bfhi(v1.y);
            g[4] += bflo(v1.z); g[5] += bfhi(v1.z);
            g[6] += bflo(v1.w); g[7] += bfhi(v1.w);
            k += 4;
        }
        if (end - k >= 2) {
            int s0 = csr[k + half];
            uint4 v0 = *(const uint4*)(xb + (size_t)s0 * D128 + fl * 8);
            f[0] += bflo(v0.x); f[1] += bfhi(v0.x);
            f[2] += bflo(v0.y); f[3] += bfhi(v0.y);
            f[4] += bflo(v0.z); f[5] += bfhi(v0.z);
            f[6] += bflo(v0.w); f[7] += bfhi(v0.w);
            k += 2;
        }
        if (k < end && half == 0) {
            int s0 = csr[k];
            uint4 v0 = *(const uint4*)(xb + (size_t)s0 * D128 + fl * 8);
            f[0] += bflo(v0.x); f[1] += bfhi(v0.x);
            f[2] += bflo(v0.y); f[3] += bfhi(v0.y);
            f[4] += bflo(v0.z); f[5] += bfhi(v0.z);
            f[6] += bflo(v0.w); f[7] += bfhi(v0.w);
        }
        if (deg > 0) inv = 1.0f / (float)deg;
    }
#pragma unroll
    for (int j = 0; j < 8; ++j) {
        f[j] += g[j];
        f[j] += __shfl_xor(f[j], 16, 64);   // combine halves (stays in group)
    }
    if (half == 0) {
        uint4 o;
        o.x = (unsigned)f2bf(f[0] * inv) | ((unsigned)f2bf(f[1] * inv) << 16);
        o.y = (unsigned)f2bf(f[2] * inv) | ((unsigned)f2bf(f[3] * inv) << 16);
        o.z = (unsigned)f2bf(f[4] * inv) | ((unsigned)f2bf(f[5] * inv) << 16);
        o.w = (unsigned)f2bf(f[6] * inv) | ((unsigned)f2bf(f[7] * inv) << 16);
        *(uint4*)(aggb + (size_t)n * D128 + fl * 8) = o;
    }
}

// --- MFMA dual GEMM -> bf16 h + BN stats into replicated accumulators ------
// K=256: ksteps 0-3 read aggb, 4-7 read xb. No b_l (cancelled by BN).
__global__ __launch_bounds__(256) void mfma_kernel(
    const unsigned short* __restrict__ aggb, const unsigned short* __restrict__ xb,
    const unsigned short* __restrict__ Bsw,
    unsigned short* __restrict__ h16, float* __restrict__ stats, int N) {
    __shared__ float red[4][256];
    int tid  = threadIdx.x;
    int w    = tid >> 6;
    int lane = tid & 63;
    int lc   = lane & 15;    // tile col
    int lq   = lane >> 4;    // quarter
    int rowBase = blockIdx.x * 128 + w * 32;

    f32x4 acc[2][8];
#pragma unroll
    for (int c = 0; c < 8; ++c) {
        f32x4 z = {0.f, 0.f, 0.f, 0.f};
        acc[0][c] = z;
        acc[1][c] = z;
    }
    int r0  = rowBase + lc;
    int r1  = rowBase + 16 + lc;
    int r0c = min(r0, N - 1);
    int r1c = min(r1, N - 1);
    for (int t = 0; t < 8; ++t) {
        const unsigned short* p0;
        const unsigned short* p1;
        if (t < 4) {
            int off = t * 32 + lq * 8;
            p0 = aggb + (size_t)r0 * D128 + off;
            p1 = aggb + (size_t)r1 * D128 + off;
        } else {
            int off = (t - 4) * 32 + lq * 8;
            p0 = xb + (size_t)r0c * D128 + off;
            p1 = xb + (size_t)r1c * D128 + off;
        }
        bf16x8 a0 = *(const bf16x8*)p0;
        bf16x8 a1 = *(const bf16x8*)p1;
#pragma unroll
        for (int c = 0; c < 8; ++c) {
            bf16x8 bf = *(const bf16x8*)(Bsw + ((size_t)((t * 8 + c) * 64 + lane)) * 8);
            acc[0][c] = __builtin_amdgcn_mfma_f32_16x16x32_bf16(a0, bf, acc[0][c], 0, 0, 0);
            acc[1][c] = __builtin_amdgcn_mfma_f32_16x16x32_bf16(a1, bf, acc[1][c], 0, 0, 0);
        }
    }
    float s[8], ss[8];
#pragma unroll
    for (int c = 0; c < 8; ++c) { s[c] = 0.f; ss[c] = 0.f; }
#pragma unroll
    for (int rh = 0; rh < 2; ++rh) {
#pragma unroll
        for (int reg = 0; reg < 4; ++reg) {
            int row = rowBase + rh * 16 + lq * 4 + reg;   // C-layout row
            if (row < N) {
#pragma unroll
                for (int c = 0; c < 8; ++c) {
                    float v = acc[rh][c][reg];
                    h16[(size_t)row * D128 + c * 16 + lc] = f2bf(v);
                    s[c]  += v;
                    ss[c] += v * v;
                }
            }
        }
    }
#pragma unroll
    for (int c = 0; c < 8; ++c) {
        s[c]  += __shfl_xor(s[c], 16, 64);
        s[c]  += __shfl_xor(s[c], 32, 64);
        ss[c] += __shfl_xor(ss[c], 16, 64);
        ss[c] += __shfl_xor(ss[c], 32, 64);
    }
    if (lq == 0) {
#pragma unroll
        for (int c = 0; c < 8; ++c) {
            red[w][c * 16 + lc]       = s[c];
            red[w][128 + c * 16 + lc] = ss[c];
        }
    }
    __syncthreads();
    float tot = red[0][tid] + red[1][tid] + red[2][tid] + red[3][tid];
    atomicAdd(&stats[(blockIdx.x & (SREP - 1)) * 256 + tid], tot);
}

// --- finalize: sum stat replicas, BN params in LDS, out = relu(...) --------
__global__ __launch_bounds__(256) void finalize_kernel(
    const unsigned short* __restrict__ h16, const unsigned short* __restrict__ xb,
    const float* __restrict__ stats, const float* __restrict__ gamma,
    const float* __restrict__ beta, float* __restrict__ out,
    long long total4, float invN) {
    __shared__ float sscl[D128];
    __shared__ float sshf[D128];
    int tid = threadIdx.x;
    if (tid < D128) {
        float sum = 0.f, sq = 0.f;
#pragma unroll
        for (int r = 0; r < SREP; ++r) {
            sum += stats[r * 256 + tid];
            sq  += stats[r * 256 + 128 + tid];
        }
        float mean = sum * invN;
        float var  = sq * invN - mean * mean;
        float istd = rsqrtf(var + 1e-5f);
        float sc   = gamma[tid] * istd;
        sscl[tid] = sc;
        sshf[tid] = beta[tid] - mean * sc;
    }
    __syncthreads();
    long long i = (long long)blockIdx.x * 256 + tid;
    if (i >= total4) return;
    int d = (int)((i * 4) & 127);
    uint2 hv = ((const uint2*)h16)[i];
    uint2 xv = ((const uint2*)xb)[i];
    float4 o;
    o.x = fmaxf(fmaf(bflo(hv.x), sscl[d],     sshf[d])     + bflo(xv.x), 0.f);
    o.y = fmaxf(fmaf(bfhi(hv.x), sscl[d + 1], sshf[d + 1]) + bfhi(xv.x), 0.f);
    o.z = fmaxf(fmaf(bflo(hv.y), sscl[d + 2], sshf[d + 2]) + bflo(xv.y), 0.f);
    o.w = fmaxf(fmaf(bfhi(hv.y), sscl[d + 3], sshf[d + 3]) + bfhi(xv.y), 0.f);
    ((float4*)out)[i] = o;
}

extern "C" void kernel_launch(void* const* d_in, const int* in_sizes, int n_in,
                              void* d_out, int out_size, void* d_ws, size_t ws_size,
                              hipStream_t stream) {
    const float* x     = (const float*)d_in[0];
    const int*   eidx  = (const int*)d_in[1];
    const float* W_l   = (const float*)d_in[2];
    const float* W_r   = (const float*)d_in[4];
    const float* gamma = (const float*)d_in[5];
    const float* beta  = (const float*)d_in[6];

    const int D = in_sizes[3];            // 128
    const int N = in_sizes[0] / D;        // 100000
    const int E = in_sizes[1] / 2;        // 1600000

    const int* src = eidx;
    const int* dst = eidx + E;

    const int NBLK  = (N + 127) / 128;        // mfma blocks (782)
    const int Npad  = NBLK * 128;             // padded rows (100096)
    const int NBUK  = (N + BSZ2 - 1) / BSZ2;  // buckets (391)
    const int M     = NBUK * SBLK;            // ghist cells (100096)
    const int NB2   = (M + 1023) / 1024;      // ghist-scan blocks (98, <=256)
    const int chunk = (E + SBLK - 1) / SBLK;  // edges per sort block (6250)
    const int total4 = N * D128 / 4;          // float4s in x

    // workspace layout (byte cursor, 64B-aligned chunks)
    char* wp = (char*)d_ws;
    auto alloc = [&](size_t bytes) {
        char* p = wp;
        wp += (bytes + 63) & ~(size_t)63;
        return p;
    };
    float*    stats = (float*)   alloc((size_t)SREP * 256 * 4);
    int*      offs  = (int*)     alloc((size_t)(N + 1) * 4);
    int*      csr   = (int*)     alloc((size_t)E * 4);
    unsigned* pairs = (unsigned*)alloc((size_t)E * 4);
    int*      ghist = (int*)     alloc((size_t)M * 4);
    int*      gsc   = (int*)     alloc((size_t)(M + 1) * 4);
    int*      bsum  = (int*)     alloc(1024 * 4);
    unsigned short* Bsw  = (unsigned short*)alloc(4096 * 16);
    unsigned short* xb   = (unsigned short*)alloc((size_t)N * D128 * 2);
    unsigned short* aggb = (unsigned short*)alloc((size_t)Npad * D128 * 2);
    unsigned short* h16  = (unsigned short*)alloc((size_t)N * D128 * 2);

    float* outp = (float*)d_out;
    float invN = 1.0f / (float)N;

    prep_kernel<<<16, 256, 0, stream>>>(W_l, W_r, Bsw, stats);

    // bucket hist (+ fused x->bf16) -> scan -> block-private scatter
    bhist_kernel<<<SBLK, 256, 0, stream>>>(dst, ghist, x, xb, E, chunk, NBUK, total4);
    partial_kernel<<<NB2, 256, 0, stream>>>(ghist, bsum, M);
    scan_final_kernel<<<NB2, 256, 0, stream>>>(ghist, bsum, gsc, M, NB2);
    bscatter_kernel<<<SBLK, 256, 0, stream>>>(src, dst, gsc, pairs, E, chunk, NBUK);

    // per-bucket CSR build (also writes offs)
    csrbuild_kernel<<<NBUK, 256, 0, stream>>>(pairs, gsc, csr, offs, N, NBUK, E);

    gather_kernel<<<Npad / 8, 256, 0, stream>>>(offs, csr, xb, aggb, N, Npad);

    mfma_kernel<<<NBLK, 256, 0, stream>>>(aggb, xb, Bsw, h16, stats, N);

    {
        long long t4 = (long long)N * D128 / 4;
        finalize_kernel<<<(int)((t4 + 255) / 256), 256, 0, stream>>>(
            h16, xb, stats, gamma, beta, outp, t4, invN);
    }
}